// Round 1
// baseline (324.559 us; speedup 1.0000x reference)
//
#include <hip/hip_runtime.h>

#define D_MODEL 1024
#define T_SEQ   1024
#define BATCH   8
#define NHEAD   16
#define HDIM    64

typedef float      v4f   __attribute__((ext_vector_type(4)));
typedef _Float16   half8 __attribute__((ext_vector_type(8)));
typedef _Float16   half4h __attribute__((ext_vector_type(4)));
typedef unsigned int ui4 __attribute__((ext_vector_type(4)));

// ---------------- LayerNorm (fp32 in) -> fp16 xn ----------------
__global__ __launch_bounds__(256) void ln_kernel(const float* __restrict__ x,
                                                 const float* __restrict__ gamma,
                                                 const float* __restrict__ beta,
                                                 _Float16* __restrict__ xn) {
  int row = blockIdx.x;
  int tid = threadIdx.x;
  const float* xr = x + (size_t)row * D_MODEL;
  v4f xv = *(const v4f*)(xr + tid * 4);
  float s  = xv[0] + xv[1] + xv[2] + xv[3];
  float sq = xv[0]*xv[0] + xv[1]*xv[1] + xv[2]*xv[2] + xv[3]*xv[3];
#pragma unroll
  for (int off = 32; off > 0; off >>= 1) {
    s  += __shfl_xor(s, off);
    sq += __shfl_xor(sq, off);
  }
  __shared__ float ps[4], psq[4];
  int wave = tid >> 6;
  if ((tid & 63) == 0) { ps[wave] = s; psq[wave] = sq; }
  __syncthreads();
  float tot  = ps[0] + ps[1] + ps[2] + ps[3];
  float totq = psq[0] + psq[1] + psq[2] + psq[3];
  float mean = tot * (1.0f / D_MODEL);
  float var  = totq * (1.0f / D_MODEL) - mean * mean;
  float rs   = rsqrtf(var + 1e-5f);
  v4f gv = *(const v4f*)(gamma + tid * 4);
  v4f bv = *(const v4f*)(beta + tid * 4);
  half4h o;
#pragma unroll
  for (int i = 0; i < 4; ++i)
    o[i] = (_Float16)((xv[i] - mean) * rs * gv[i] + bv[i]);
  *(half4h*)(xn + (size_t)row * D_MODEL + tid * 4) = o;
}

// ------------- transpose fp32 (R x C) -> fp16 (C x R) -------------
__global__ __launch_bounds__(256) void transpose_kernel(const float* __restrict__ W,
                                                        _Float16* __restrict__ Wt,
                                                        int R, int C) {
  __shared__ float tile[32][33];
  int c0 = blockIdx.x * 32, r0 = blockIdx.y * 32;
  int tx = threadIdx.x & 31, ty = threadIdx.x >> 5;
#pragma unroll
  for (int i = 0; i < 4; ++i)
    tile[ty + i * 8][tx] = W[(size_t)(r0 + ty + i * 8) * C + c0 + tx];
  __syncthreads();
#pragma unroll
  for (int i = 0; i < 4; ++i)
    Wt[(size_t)(c0 + ty + i * 8) * R + r0 + tx] = (_Float16)tile[tx][ty + i * 8];
}

// ---------------- 128x128 MFMA GEMM, A(MxK) * Bt(NxK)^T ----------------
// MODE 0: epilogue scatters QKV -> Q(B,H,T,64)*0.125, K(B,H,T,64), V^T(B,H,64,T)
// MODE 1: epilogue writes fp32 out + bias
template <int MODE>
__global__ __launch_bounds__(256) void gemm_kernel(
    const _Float16* __restrict__ A, const _Float16* __restrict__ Bt,
    const float* __restrict__ bias, int M, int N, int K,
    float* __restrict__ outF,
    _Float16* __restrict__ Qd, _Float16* __restrict__ Kd, _Float16* __restrict__ Vtd) {
  __shared__ _Float16 As[128 * 32];
  __shared__ _Float16 Bs[128 * 32];
  int tid = threadIdx.x;
  int wave = tid >> 6, lane = tid & 63;
  int l15 = lane & 15, quad = lane >> 4;
  int wm = (wave & 1) * 64, wn = (wave >> 1) * 64;
  int n0 = blockIdx.x * 128, m0 = blockIdx.y * 128;
  v4f zero = {0.f, 0.f, 0.f, 0.f};
  v4f acc[4][4];
#pragma unroll
  for (int i = 0; i < 4; ++i)
#pragma unroll
    for (int j = 0; j < 4; ++j) acc[i][j] = zero;

  int ar0 = tid >> 2;          // rows 0..63 (second chunk +64)
  int akc = (tid & 3) * 8;     // k offset within 32
  for (int kt = 0; kt < K; kt += 32) {
    __syncthreads();
#pragma unroll
    for (int it = 0; it < 2; ++it) {
      int r = ar0 + it * 64;
      *(ui4*)&As[r * 32 + akc] = *(const ui4*)&A[(size_t)(m0 + r) * K + kt + akc];
      *(ui4*)&Bs[r * 32 + akc] = *(const ui4*)&Bt[(size_t)(n0 + r) * K + kt + akc];
    }
    __syncthreads();
    half8 af[4], bf[4];
#pragma unroll
    for (int i = 0; i < 4; ++i) {
      af[i] = *(const half8*)&As[(wm + i * 16 + l15) * 32 + quad * 8];
      bf[i] = *(const half8*)&Bs[(wn + i * 16 + l15) * 32 + quad * 8];
    }
#pragma unroll
    for (int mi = 0; mi < 4; ++mi)
#pragma unroll
      for (int ni = 0; ni < 4; ++ni)
        acc[mi][ni] = __builtin_amdgcn_mfma_f32_16x16x32_f16(af[mi], bf[ni], acc[mi][ni], 0, 0, 0);
  }
  // epilogue: C layout row=quad*4+r, col=l15
  float bv[4];
#pragma unroll
  for (int ni = 0; ni < 4; ++ni) bv[ni] = bias[n0 + wn + ni * 16 + l15];
#pragma unroll
  for (int mi = 0; mi < 4; ++mi) {
#pragma unroll
    for (int ni = 0; ni < 4; ++ni) {
      int n = n0 + wn + ni * 16 + l15;
#pragma unroll
      for (int r = 0; r < 4; ++r) {
        int m = m0 + wm + mi * 16 + quad * 4 + r;
        float v = acc[mi][ni][r] + bv[ni];
        if (MODE == 1) {
          outF[(size_t)m * N + n] = v;
        } else {
          int b = m >> 10, t = m & 1023;
          if (n < 1024) {
            int h = n >> 6, d = n & 63;
            Qd[((size_t)(b * NHEAD + h) * T_SEQ + t) * HDIM + d] = (_Float16)(v * 0.125f);
          } else if (n < 2048) {
            int h = (n - 1024) >> 6, d = n & 63;
            Kd[((size_t)(b * NHEAD + h) * T_SEQ + t) * HDIM + d] = (_Float16)v;
          } else {
            int h = (n - 2048) >> 6, d = n & 63;
            Vtd[((size_t)(b * NHEAD + h) * HDIM + d) * T_SEQ + t] = (_Float16)v;
          }
        }
      }
    }
  }
}

// ---------------- flash attention: 64 q-rows/block, 64-key tiles ----------------
__global__ __launch_bounds__(256) void attn_kernel(const _Float16* __restrict__ Q,
                                                   const _Float16* __restrict__ K,
                                                   const _Float16* __restrict__ Vt,
                                                   const int* __restrict__ x_lens,
                                                   _Float16* __restrict__ att) {
  __shared__ _Float16 Ks[64 * 72];      // [key][dim], stride 72 (bank spread)
  __shared__ _Float16 Vs[64 * 72];      // [dim][key]
  __shared__ _Float16 Pb[4][16 * 72];   // per-wave P round-trip
  int blk = blockIdx.x;
  int qt = blk & 15;
  int h  = (blk >> 4) & 15;
  int b  = blk >> 8;
  int t0 = qt * 64;
  int len = x_lens[b];
  int tid = threadIdx.x;
  int wave = tid >> 6, lane = tid & 63;
  int l15 = lane & 15, quad = lane >> 4;
  size_t plane = (size_t)(b * NHEAD + h) * (T_SEQ * HDIM);
  int qrow = t0 + wave * 16;
  const _Float16* Qp = Q + plane + (size_t)(qrow + l15) * HDIM + quad * 8;
  half8 qf0 = *(const half8*)Qp;
  half8 qf1 = *(const half8*)(Qp + 32);
  v4f zero = {0.f, 0.f, 0.f, 0.f};
  float m_i[4], l_i[4];
  v4f Ov[4];
#pragma unroll
  for (int r = 0; r < 4; ++r) { m_i[r] = -1e30f; l_i[r] = 0.f; }
#pragma unroll
  for (int nt = 0; nt < 4; ++nt) Ov[nt] = zero;

  int jmax  = min(t0 + 63, len - 1);
  int ntile = (jmax >> 6) + 1;
  int vr = tid >> 3;            // stage rows 0..31 (+32 on second chunk)
  int vc = (tid & 7) * 8;
  for (int jt = 0; jt < ntile; ++jt) {
    int j0 = jt * 64;
    __syncthreads();
#pragma unroll
    for (int it = 0; it < 2; ++it) {
      int r = vr + it * 32;
      *(ui4*)&Ks[r * 72 + vc] = *(const ui4*)&K[plane + (size_t)(j0 + r) * HDIM + vc];
      *(ui4*)&Vs[r * 72 + vc] = *(const ui4*)&Vt[plane + (size_t)r * T_SEQ + j0 + vc];
    }
    __syncthreads();
    // S = Q K^T  (scale folded into Q)
    v4f s[4];
#pragma unroll
    for (int nt = 0; nt < 4; ++nt) {
      s[nt] = zero;
      half8 k0 = *(const half8*)&Ks[(nt * 16 + l15) * 72 + quad * 8];
      half8 k1 = *(const half8*)&Ks[(nt * 16 + l15) * 72 + quad * 8 + 32];
      s[nt] = __builtin_amdgcn_mfma_f32_16x16x32_f16(qf0, k0, s[nt], 0, 0, 0);
      s[nt] = __builtin_amdgcn_mfma_f32_16x16x32_f16(qf1, k1, s[nt], 0, 0, 0);
    }
    // mask + online softmax (rows = quad*4+r, cols = j0 + nt*16 + l15)
    float rmax[4] = {-1e30f, -1e30f, -1e30f, -1e30f};
#pragma unroll
    for (int nt = 0; nt < 4; ++nt) {
      int col = j0 + nt * 16 + l15;
#pragma unroll
      for (int r = 0; r < 4; ++r) {
        int trow = qrow + quad * 4 + r;
        float v = (col <= trow && col < len) ? s[nt][r] : -1e30f;
        s[nt][r] = v;
        rmax[r] = fmaxf(rmax[r], v);
      }
    }
#pragma unroll
    for (int off = 1; off < 16; off <<= 1)
#pragma unroll
      for (int r = 0; r < 4; ++r)
        rmax[r] = fmaxf(rmax[r], __shfl_xor(rmax[r], off));
    float alpha[4], rsum[4];
#pragma unroll
    for (int r = 0; r < 4; ++r) {
      float mn = fmaxf(m_i[r], rmax[r]);
      alpha[r] = __expf(m_i[r] - mn);
      m_i[r] = mn;
      rsum[r] = 0.f;
    }
#pragma unroll
    for (int nt = 0; nt < 4; ++nt)
#pragma unroll
      for (int r = 0; r < 4; ++r) {
        float p = __expf(s[nt][r] - m_i[r]);
        s[nt][r] = p;
        rsum[r] += p;
      }
#pragma unroll
    for (int off = 1; off < 16; off <<= 1)
#pragma unroll
      for (int r = 0; r < 4; ++r)
        rsum[r] += __shfl_xor(rsum[r], off);
#pragma unroll
    for (int r = 0; r < 4; ++r) l_i[r] = l_i[r] * alpha[r] + rsum[r];
#pragma unroll
    for (int nt = 0; nt < 4; ++nt)
#pragma unroll
      for (int r = 0; r < 4; ++r) Ov[nt][r] *= alpha[r];
    // P: C-layout -> LDS -> A-layout
#pragma unroll
    for (int nt = 0; nt < 4; ++nt)
#pragma unroll
      for (int r = 0; r < 4; ++r)
        Pb[wave][(quad * 4 + r) * 72 + nt * 16 + l15] = (_Float16)s[nt][r];
    __syncthreads();
    half8 p0 = *(const half8*)&Pb[wave][l15 * 72 + quad * 8];
    half8 p1 = *(const half8*)&Pb[wave][l15 * 72 + quad * 8 + 32];
#pragma unroll
    for (int nt = 0; nt < 4; ++nt) {
      half8 v0 = *(const half8*)&Vs[(nt * 16 + l15) * 72 + quad * 8];
      half8 v1 = *(const half8*)&Vs[(nt * 16 + l15) * 72 + quad * 8 + 32];
      Ov[nt] = __builtin_amdgcn_mfma_f32_16x16x32_f16(p0, v0, Ov[nt], 0, 0, 0);
      Ov[nt] = __builtin_amdgcn_mfma_f32_16x16x32_f16(p1, v1, Ov[nt], 0, 0, 0);
    }
  }
  float inv[4];
#pragma unroll
  for (int r = 0; r < 4; ++r) inv[r] = 1.0f / l_i[r];
#pragma unroll
  for (int nt = 0; nt < 4; ++nt)
#pragma unroll
    for (int r = 0; r < 4; ++r) {
      int trow = qrow + quad * 4 + r;
      att[((size_t)(b * T_SEQ) + trow) * D_MODEL + h * HDIM + nt * 16 + l15] =
          (_Float16)(Ov[nt][r] * inv[r]);
    }
}

extern "C" void kernel_launch(void* const* d_in, const int* in_sizes, int n_in,
                              void* d_out, int out_size, void* d_ws, size_t ws_size,
                              hipStream_t stream) {
  const float* x        = (const float*)d_in[0];
  const int*   x_lens   = (const int*)d_in[1];
  const float* ln_gamma = (const float*)d_in[2];
  const float* ln_beta  = (const float*)d_in[3];
  const float* w_qkv    = (const float*)d_in[4];
  const float* b_qkv    = (const float*)d_in[5];
  const float* w_out    = (const float*)d_in[6];
  const float* b_out    = (const float*)d_in[7];
  float* out = (float*)d_out;

  char* w = (char*)d_ws;
  _Float16* xn    = (_Float16*)w; w += (size_t)8192 * 1024 * 2;
  _Float16* wqkvT = (_Float16*)w; w += (size_t)3072 * 1024 * 2;
  _Float16* woutT = (_Float16*)w; w += (size_t)1024 * 1024 * 2;
  _Float16* Qd    = (_Float16*)w; w += (size_t)8192 * 1024 * 2;
  _Float16* Kd    = (_Float16*)w; w += (size_t)8192 * 1024 * 2;
  _Float16* Vtd   = (_Float16*)w; w += (size_t)8192 * 1024 * 2;
  _Float16* att   = (_Float16*)w; w += (size_t)8192 * 1024 * 2;

  transpose_kernel<<<dim3(3072 / 32, 1024 / 32), 256, 0, stream>>>(w_qkv, wqkvT, 1024, 3072);
  transpose_kernel<<<dim3(1024 / 32, 1024 / 32), 256, 0, stream>>>(w_out, woutT, 1024, 1024);
  ln_kernel<<<8192, 256, 0, stream>>>(x, ln_gamma, ln_beta, xn);
  gemm_kernel<0><<<dim3(3072 / 128, 8192 / 128), 256, 0, stream>>>(
      xn, wqkvT, b_qkv, 8192, 3072, 1024, nullptr, Qd, Kd, Vtd);
  attn_kernel<<<2048, 256, 0, stream>>>(Qd, Kd, Vtd, x_lens, att);
  gemm_kernel<1><<<dim3(1024 / 128, 8192 / 128), 256, 0, stream>>>(
      att, woutT, b_out, 8192, 1024, 1024, out, nullptr, nullptr, nullptr);
}

// Round 2
// 315.194 us; speedup vs baseline: 1.0297x; 1.0297x over previous
//
#include <hip/hip_runtime.h>

#define D_MODEL 1024
#define T_SEQ   1024
#define BATCH   8
#define NHEAD   16
#define HDIM    64

typedef float      v4f   __attribute__((ext_vector_type(4)));
typedef _Float16   half8 __attribute__((ext_vector_type(8)));
typedef _Float16   half4h __attribute__((ext_vector_type(4)));
typedef unsigned int ui4 __attribute__((ext_vector_type(4)));

// async global->LDS, 16B per lane, dest = wave-uniform base + lane*16
__device__ __forceinline__ void load_lds16(const _Float16* g, _Float16* l) {
  __builtin_amdgcn_global_load_lds(
      (const __attribute__((address_space(1))) unsigned int*)g,
      (__attribute__((address_space(3))) unsigned int*)l, 16, 0, 0);
}

// ---------------- LayerNorm (fp32 in) -> fp16 xn ----------------
__global__ __launch_bounds__(256) void ln_kernel(const float* __restrict__ x,
                                                 const float* __restrict__ gamma,
                                                 const float* __restrict__ beta,
                                                 _Float16* __restrict__ xn) {
  int row = blockIdx.x;
  int tid = threadIdx.x;
  const float* xr = x + (size_t)row * D_MODEL;
  v4f xv = *(const v4f*)(xr + tid * 4);
  float s  = xv[0] + xv[1] + xv[2] + xv[3];
  float sq = xv[0]*xv[0] + xv[1]*xv[1] + xv[2]*xv[2] + xv[3]*xv[3];
#pragma unroll
  for (int off = 32; off > 0; off >>= 1) {
    s  += __shfl_xor(s, off);
    sq += __shfl_xor(sq, off);
  }
  __shared__ float ps[4], psq[4];
  int wave = tid >> 6;
  if ((tid & 63) == 0) { ps[wave] = s; psq[wave] = sq; }
  __syncthreads();
  float tot  = ps[0] + ps[1] + ps[2] + ps[3];
  float totq = psq[0] + psq[1] + psq[2] + psq[3];
  float mean = tot * (1.0f / D_MODEL);
  float var  = totq * (1.0f / D_MODEL) - mean * mean;
  float rs   = rsqrtf(var + 1e-5f);
  v4f gv = *(const v4f*)(gamma + tid * 4);
  v4f bv = *(const v4f*)(beta + tid * 4);
  half4h o;
#pragma unroll
  for (int i = 0; i < 4; ++i)
    o[i] = (_Float16)((xv[i] - mean) * rs * gv[i] + bv[i]);
  *(half4h*)(xn + (size_t)row * D_MODEL + tid * 4) = o;
}

// ------------- transpose fp32 (R x C) -> fp16 (C x R) -------------
__global__ __launch_bounds__(256) void transpose_kernel(const float* __restrict__ W,
                                                        _Float16* __restrict__ Wt,
                                                        int R, int C) {
  __shared__ float tile[32][33];
  int c0 = blockIdx.x * 32, r0 = blockIdx.y * 32;
  int tx = threadIdx.x & 31, ty = threadIdx.x >> 5;
#pragma unroll
  for (int i = 0; i < 4; ++i)
    tile[ty + i * 8][tx] = W[(size_t)(r0 + ty + i * 8) * C + c0 + tx];
  __syncthreads();
#pragma unroll
  for (int i = 0; i < 4; ++i)
    Wt[(size_t)(c0 + ty + i * 8) * R + r0 + tx] = (_Float16)tile[tx][ty + i * 8];
}

// ---------------- 128x128 MFMA GEMM, A(MxK) * Bt(NxK)^T ----------------
// Staging via global_load_lds width=16 (m97 pattern).
// MODE 0: epilogue scatters QKV -> Q(B,H,T,64)*0.125, K(B,H,T,64), V^T(B,H,64,T)
// MODE 1: epilogue writes fp32 out + bias
template <int MODE>
__global__ __launch_bounds__(256) void gemm_kernel(
    const _Float16* __restrict__ A, const _Float16* __restrict__ Bt,
    const float* __restrict__ bias, int M, int N, int K,
    float* __restrict__ outF,
    _Float16* __restrict__ Qd, _Float16* __restrict__ Kd, _Float16* __restrict__ Vtd) {
  __shared__ _Float16 As[128 * 32];
  __shared__ _Float16 Bs[128 * 32];
  int tid = threadIdx.x;
  int wave = tid >> 6, lane = tid & 63;
  int l15 = lane & 15, quad = lane >> 4;
  int wm = (wave & 1) * 64, wn = (wave >> 1) * 64;
  int n0 = blockIdx.x * 128, m0 = blockIdx.y * 128;
  v4f zero = {0.f, 0.f, 0.f, 0.f};
  v4f acc[4][4];
#pragma unroll
  for (int i = 0; i < 4; ++i)
#pragma unroll
    for (int j = 0; j < 4; ++j) acc[i][j] = zero;

  int ar0 = tid >> 2;          // per-block row 0..63 (chunk 1: +64); wave w covers rows w*16..w*16+15
  int akc = (tid & 3) * 8;     // k offset within 32
  const _Float16* Ap = A  + (size_t)(m0 + ar0) * K + akc;
  const _Float16* Bp = Bt + (size_t)(n0 + ar0) * K + akc;
  _Float16* AsW = As + wave * 512;   // wave-uniform LDS bases (lane L lands at +L*16B)
  _Float16* BsW = Bs + wave * 512;
  for (int kt = 0; kt < K; kt += 32) {
    __syncthreads();
    load_lds16(Ap + kt,                    AsW);
    load_lds16(Ap + kt + (size_t)64 * K,   AsW + 2048);
    load_lds16(Bp + kt,                    BsW);
    load_lds16(Bp + kt + (size_t)64 * K,   BsW + 2048);
    __syncthreads();
    half8 af[4], bf[4];
#pragma unroll
    for (int i = 0; i < 4; ++i) {
      af[i] = *(const half8*)&As[(wm + i * 16 + l15) * 32 + quad * 8];
      bf[i] = *(const half8*)&Bs[(wn + i * 16 + l15) * 32 + quad * 8];
    }
#pragma unroll
    for (int mi = 0; mi < 4; ++mi)
#pragma unroll
      for (int ni = 0; ni < 4; ++ni)
        acc[mi][ni] = __builtin_amdgcn_mfma_f32_16x16x32_f16(af[mi], bf[ni], acc[mi][ni], 0, 0, 0);
  }
  // epilogue: C layout row=quad*4+r, col=l15
  float bv[4];
#pragma unroll
  for (int ni = 0; ni < 4; ++ni) bv[ni] = bias[n0 + wn + ni * 16 + l15];
#pragma unroll
  for (int mi = 0; mi < 4; ++mi) {
#pragma unroll
    for (int ni = 0; ni < 4; ++ni) {
      int n = n0 + wn + ni * 16 + l15;
#pragma unroll
      for (int r = 0; r < 4; ++r) {
        int m = m0 + wm + mi * 16 + quad * 4 + r;
        float v = acc[mi][ni][r] + bv[ni];
        if (MODE == 1) {
          outF[(size_t)m * N + n] = v;
        } else {
          int b = m >> 10, t = m & 1023;
          if (n < 1024) {
            int h = n >> 6, d = n & 63;
            Qd[((size_t)(b * NHEAD + h) * T_SEQ + t) * HDIM + d] = (_Float16)(v * 0.125f);
          } else if (n < 2048) {
            int h = (n - 1024) >> 6, d = n & 63;
            Kd[((size_t)(b * NHEAD + h) * T_SEQ + t) * HDIM + d] = (_Float16)v;
          } else {
            int h = (n - 2048) >> 6, d = n & 63;
            Vtd[((size_t)(b * NHEAD + h) * HDIM + d) * T_SEQ + t] = (_Float16)v;
          }
        }
      }
    }
  }
}

// ---------------- flash attention: 64 q-rows/block, 64-key tiles ----------------
__global__ __launch_bounds__(256) void attn_kernel(const _Float16* __restrict__ Q,
                                                   const _Float16* __restrict__ K,
                                                   const _Float16* __restrict__ Vt,
                                                   const int* __restrict__ x_lens,
                                                   _Float16* __restrict__ att) {
  __shared__ _Float16 Ks[64 * 72];      // [key][dim], stride 72 (bank spread)
  __shared__ _Float16 Vs[64 * 72];      // [dim][key]
  __shared__ _Float16 Pb[4][16 * 72];   // per-wave P round-trip
  int blk = blockIdx.x;
  int qt = blk & 15;
  int h  = (blk >> 4) & 15;
  int b  = blk >> 8;
  int t0 = qt * 64;
  int len = x_lens[b];
  int tid = threadIdx.x;
  int wave = tid >> 6, lane = tid & 63;
  int l15 = lane & 15, quad = lane >> 4;
  size_t plane = (size_t)(b * NHEAD + h) * (T_SEQ * HDIM);
  int qrow = t0 + wave * 16;
  const _Float16* Qp = Q + plane + (size_t)(qrow + l15) * HDIM + quad * 8;
  half8 qf0 = *(const half8*)Qp;
  half8 qf1 = *(const half8*)(Qp + 32);
  v4f zero = {0.f, 0.f, 0.f, 0.f};
  float m_i[4], l_i[4];
  v4f Ov[4];
#pragma unroll
  for (int r = 0; r < 4; ++r) { m_i[r] = -1e30f; l_i[r] = 0.f; }
#pragma unroll
  for (int nt = 0; nt < 4; ++nt) Ov[nt] = zero;

  int jmax  = min(t0 + 63, len - 1);
  int ntile = (jmax >> 6) + 1;
  int vr = tid >> 3;            // stage rows 0..31 (+32 on second chunk)
  int vc = (tid & 7) * 8;
  for (int jt = 0; jt < ntile; ++jt) {
    int j0 = jt * 64;
    __syncthreads();
#pragma unroll
    for (int it = 0; it < 2; ++it) {
      int r = vr + it * 32;
      *(ui4*)&Ks[r * 72 + vc] = *(const ui4*)&K[plane + (size_t)(j0 + r) * HDIM + vc];
      *(ui4*)&Vs[r * 72 + vc] = *(const ui4*)&Vt[plane + (size_t)r * T_SEQ + j0 + vc];
    }
    __syncthreads();
    // S = Q K^T  (scale folded into Q)
    v4f s[4];
#pragma unroll
    for (int nt = 0; nt < 4; ++nt) {
      s[nt] = zero;
      half8 k0 = *(const half8*)&Ks[(nt * 16 + l15) * 72 + quad * 8];
      half8 k1 = *(const half8*)&Ks[(nt * 16 + l15) * 72 + quad * 8 + 32];
      s[nt] = __builtin_amdgcn_mfma_f32_16x16x32_f16(qf0, k0, s[nt], 0, 0, 0);
      s[nt] = __builtin_amdgcn_mfma_f32_16x16x32_f16(qf1, k1, s[nt], 0, 0, 0);
    }
    // mask + online softmax (rows = quad*4+r, cols = j0 + nt*16 + l15)
    float rmax[4] = {-1e30f, -1e30f, -1e30f, -1e30f};
#pragma unroll
    for (int nt = 0; nt < 4; ++nt) {
      int col = j0 + nt * 16 + l15;
#pragma unroll
      for (int r = 0; r < 4; ++r) {
        int trow = qrow + quad * 4 + r;
        float v = (col <= trow && col < len) ? s[nt][r] : -1e30f;
        s[nt][r] = v;
        rmax[r] = fmaxf(rmax[r], v);
      }
    }
#pragma unroll
    for (int off = 1; off < 16; off <<= 1)
#pragma unroll
      for (int r = 0; r < 4; ++r)
        rmax[r] = fmaxf(rmax[r], __shfl_xor(rmax[r], off));
    float alpha[4], rsum[4];
#pragma unroll
    for (int r = 0; r < 4; ++r) {
      float mn = fmaxf(m_i[r], rmax[r]);
      alpha[r] = __expf(m_i[r] - mn);
      m_i[r] = mn;
      rsum[r] = 0.f;
    }
#pragma unroll
    for (int nt = 0; nt < 4; ++nt)
#pragma unroll
      for (int r = 0; r < 4; ++r) {
        float p = __expf(s[nt][r] - m_i[r]);
        s[nt][r] = p;
        rsum[r] += p;
      }
#pragma unroll
    for (int off = 1; off < 16; off <<= 1)
#pragma unroll
      for (int r = 0; r < 4; ++r)
        rsum[r] += __shfl_xor(rsum[r], off);
#pragma unroll
    for (int r = 0; r < 4; ++r) l_i[r] = l_i[r] * alpha[r] + rsum[r];
#pragma unroll
    for (int nt = 0; nt < 4; ++nt)
#pragma unroll
      for (int r = 0; r < 4; ++r) Ov[nt][r] *= alpha[r];
    // P: C-layout -> LDS -> A-layout
#pragma unroll
    for (int nt = 0; nt < 4; ++nt)
#pragma unroll
      for (int r = 0; r < 4; ++r)
        Pb[wave][(quad * 4 + r) * 72 + nt * 16 + l15] = (_Float16)s[nt][r];
    __syncthreads();
    half8 p0 = *(const half8*)&Pb[wave][l15 * 72 + quad * 8];
    half8 p1 = *(const half8*)&Pb[wave][l15 * 72 + quad * 8 + 32];
#pragma unroll
    for (int nt = 0; nt < 4; ++nt) {
      half8 v0 = *(const half8*)&Vs[(nt * 16 + l15) * 72 + quad * 8];
      half8 v1 = *(const half8*)&Vs[(nt * 16 + l15) * 72 + quad * 8 + 32];
      Ov[nt] = __builtin_amdgcn_mfma_f32_16x16x32_f16(p0, v0, Ov[nt], 0, 0, 0);
      Ov[nt] = __builtin_amdgcn_mfma_f32_16x16x32_f16(p1, v1, Ov[nt], 0, 0, 0);
    }
  }
  float inv[4];
#pragma unroll
  for (int r = 0; r < 4; ++r) inv[r] = 1.0f / l_i[r];
#pragma unroll
  for (int nt = 0; nt < 4; ++nt)
#pragma unroll
    for (int r = 0; r < 4; ++r) {
      int trow = qrow + quad * 4 + r;
      att[((size_t)(b * T_SEQ) + trow) * D_MODEL + h * HDIM + nt * 16 + l15] =
          (_Float16)(Ov[nt][r] * inv[r]);
    }
}

extern "C" void kernel_launch(void* const* d_in, const int* in_sizes, int n_in,
                              void* d_out, int out_size, void* d_ws, size_t ws_size,
                              hipStream_t stream) {
  const float* x        = (const float*)d_in[0];
  const int*   x_lens   = (const int*)d_in[1];
  const float* ln_gamma = (const float*)d_in[2];
  const float* ln_beta  = (const float*)d_in[3];
  const float* w_qkv    = (const float*)d_in[4];
  const float* b_qkv    = (const float*)d_in[5];
  const float* w_out    = (const float*)d_in[6];
  const float* b_out    = (const float*)d_in[7];
  float* out = (float*)d_out;

  char* w = (char*)d_ws;
  _Float16* xn    = (_Float16*)w; w += (size_t)8192 * 1024 * 2;
  _Float16* wqkvT = (_Float16*)w; w += (size_t)3072 * 1024 * 2;
  _Float16* woutT = (_Float16*)w; w += (size_t)1024 * 1024 * 2;
  _Float16* Qd    = (_Float16*)w; w += (size_t)8192 * 1024 * 2;
  _Float16* Kd    = (_Float16*)w; w += (size_t)8192 * 1024 * 2;
  _Float16* Vtd   = (_Float16*)w; w += (size_t)8192 * 1024 * 2;
  _Float16* att   = (_Float16*)w; w += (size_t)8192 * 1024 * 2;

  transpose_kernel<<<dim3(3072 / 32, 1024 / 32), 256, 0, stream>>>(w_qkv, wqkvT, 1024, 3072);
  transpose_kernel<<<dim3(1024 / 32, 1024 / 32), 256, 0, stream>>>(w_out, woutT, 1024, 1024);
  ln_kernel<<<8192, 256, 0, stream>>>(x, ln_gamma, ln_beta, xn);
  gemm_kernel<0><<<dim3(3072 / 128, 8192 / 128), 256, 0, stream>>>(
      xn, wqkvT, b_qkv, 8192, 3072, 1024, nullptr, Qd, Kd, Vtd);
  attn_kernel<<<2048, 256, 0, stream>>>(Qd, Kd, Vtd, x_lens, att);
  gemm_kernel<1><<<dim3(1024 / 128, 8192 / 128), 256, 0, stream>>>(
      att, woutT, b_out, 8192, 1024, 1024, out, nullptr, nullptr, nullptr);
}

// Round 3
// 312.755 us; speedup vs baseline: 1.0377x; 1.0078x over previous
//
#include <hip/hip_runtime.h>

#define D_MODEL 1024
#define T_SEQ   1024
#define BATCH   8
#define NHEAD   16
#define HDIM    64

typedef float      v4f   __attribute__((ext_vector_type(4)));
typedef _Float16   half8 __attribute__((ext_vector_type(8)));
typedef _Float16   half4h __attribute__((ext_vector_type(4)));
typedef unsigned int ui4 __attribute__((ext_vector_type(4)));

// async global->LDS, 16B per lane, dest = wave-uniform base + lane*16
__device__ __forceinline__ void load_lds16(const _Float16* g, _Float16* l) {
  __builtin_amdgcn_global_load_lds(
      (const __attribute__((address_space(1))) unsigned int*)g,
      (__attribute__((address_space(3))) unsigned int*)l, 16, 0, 0);
}

// ---------------- LayerNorm (fp32 in) -> fp16 xn ----------------
__global__ __launch_bounds__(256) void ln_kernel(const float* __restrict__ x,
                                                 const float* __restrict__ gamma,
                                                 const float* __restrict__ beta,
                                                 _Float16* __restrict__ xn) {
  int row = blockIdx.x;
  int tid = threadIdx.x;
  const float* xr = x + (size_t)row * D_MODEL;
  v4f xv = *(const v4f*)(xr + tid * 4);
  float s  = xv[0] + xv[1] + xv[2] + xv[3];
  float sq = xv[0]*xv[0] + xv[1]*xv[1] + xv[2]*xv[2] + xv[3]*xv[3];
#pragma unroll
  for (int off = 32; off > 0; off >>= 1) {
    s  += __shfl_xor(s, off);
    sq += __shfl_xor(sq, off);
  }
  __shared__ float ps[4], psq[4];
  int wave = tid >> 6;
  if ((tid & 63) == 0) { ps[wave] = s; psq[wave] = sq; }
  __syncthreads();
  float tot  = ps[0] + ps[1] + ps[2] + ps[3];
  float totq = psq[0] + psq[1] + psq[2] + psq[3];
  float mean = tot * (1.0f / D_MODEL);
  float var  = totq * (1.0f / D_MODEL) - mean * mean;
  float rs   = rsqrtf(var + 1e-5f);
  v4f gv = *(const v4f*)(gamma + tid * 4);
  v4f bv = *(const v4f*)(beta + tid * 4);
  half4h o;
#pragma unroll
  for (int i = 0; i < 4; ++i)
    o[i] = (_Float16)((xv[i] - mean) * rs * gv[i] + bv[i]);
  *(half4h*)(xn + (size_t)row * D_MODEL + tid * 4) = o;
}

// ------------- transpose fp32 (R x C) -> fp16 (C x R) -------------
__global__ __launch_bounds__(256) void transpose_kernel(const float* __restrict__ W,
                                                        _Float16* __restrict__ Wt,
                                                        int R, int C) {
  __shared__ float tile[32][33];
  int c0 = blockIdx.x * 32, r0 = blockIdx.y * 32;
  int tx = threadIdx.x & 31, ty = threadIdx.x >> 5;
#pragma unroll
  for (int i = 0; i < 4; ++i)
    tile[ty + i * 8][tx] = W[(size_t)(r0 + ty + i * 8) * C + c0 + tx];
  __syncthreads();
#pragma unroll
  for (int i = 0; i < 4; ++i)
    Wt[(size_t)(c0 + ty + i * 8) * R + r0 + tx] = (_Float16)tile[tx][ty + i * 8];
}

// ---------------- 128x128 MFMA GEMM, BK=64 (two BK=32 sub-tiles per barrier) ----
// MODE 0: epilogue scatters QKV -> Q(B,H,T,64)*0.125, K(B,H,T,64), V^T(B,H,64,T)
// MODE 1: epilogue writes fp32 out + bias
template <int MODE>
__global__ __launch_bounds__(256) void gemm_kernel(
    const _Float16* __restrict__ A, const _Float16* __restrict__ Bt,
    const float* __restrict__ bias, int M, int N, int K,
    float* __restrict__ outF,
    _Float16* __restrict__ Qd, _Float16* __restrict__ Kd, _Float16* __restrict__ Vtd) {
  __shared__ _Float16 As[2][128 * 32];   // [k-half][row*32 + chunk]
  __shared__ _Float16 Bs[2][128 * 32];
  int tid = threadIdx.x;
  int wave = tid >> 6, lane = tid & 63;
  int l15 = lane & 15, quad = lane >> 4;
  int wm = (wave & 1) * 64, wn = (wave >> 1) * 64;
  int n0 = blockIdx.x * 128, m0 = blockIdx.y * 128;
  v4f zero = {0.f, 0.f, 0.f, 0.f};
  v4f acc[4][4];
#pragma unroll
  for (int i = 0; i < 4; ++i)
#pragma unroll
    for (int j = 0; j < 4; ++j) acc[i][j] = zero;

  int ar0 = tid >> 2;          // per-block row 0..63 (chunk 1: +64)
  int akc = (tid & 3) * 8;     // k offset within 32
  const _Float16* Ap = A  + (size_t)(m0 + ar0) * K + akc;
  const _Float16* Bp = Bt + (size_t)(n0 + ar0) * K + akc;
  _Float16* AsW0 = &As[0][0] + wave * 512;   // lane L lands at +L*16B
  _Float16* BsW0 = &Bs[0][0] + wave * 512;
  _Float16* AsW1 = &As[1][0] + wave * 512;
  _Float16* BsW1 = &Bs[1][0] + wave * 512;
  for (int kt = 0; kt < K; kt += 64) {
    __syncthreads();
    load_lds16(Ap + kt,                         AsW0);
    load_lds16(Ap + kt + (size_t)64 * K,        AsW0 + 2048);
    load_lds16(Bp + kt,                         BsW0);
    load_lds16(Bp + kt + (size_t)64 * K,        BsW0 + 2048);
    load_lds16(Ap + kt + 32,                    AsW1);
    load_lds16(Ap + kt + 32 + (size_t)64 * K,   AsW1 + 2048);
    load_lds16(Bp + kt + 32,                    BsW1);
    load_lds16(Bp + kt + 32 + (size_t)64 * K,   BsW1 + 2048);
    __syncthreads();
#pragma unroll
    for (int h = 0; h < 2; ++h) {
      half8 af[4], bf[4];
#pragma unroll
      for (int i = 0; i < 4; ++i) {
        af[i] = *(const half8*)&As[h][(wm + i * 16 + l15) * 32 + quad * 8];
        bf[i] = *(const half8*)&Bs[h][(wn + i * 16 + l15) * 32 + quad * 8];
      }
#pragma unroll
      for (int mi = 0; mi < 4; ++mi)
#pragma unroll
        for (int ni = 0; ni < 4; ++ni)
          acc[mi][ni] = __builtin_amdgcn_mfma_f32_16x16x32_f16(af[mi], bf[ni], acc[mi][ni], 0, 0, 0);
    }
  }
  // epilogue: C layout row=quad*4+r, col=l15
  float bv[4];
#pragma unroll
  for (int ni = 0; ni < 4; ++ni) bv[ni] = bias[n0 + wn + ni * 16 + l15];
#pragma unroll
  for (int mi = 0; mi < 4; ++mi) {
#pragma unroll
    for (int ni = 0; ni < 4; ++ni) {
      int n = n0 + wn + ni * 16 + l15;
#pragma unroll
      for (int r = 0; r < 4; ++r) {
        int m = m0 + wm + mi * 16 + quad * 4 + r;
        float v = acc[mi][ni][r] + bv[ni];
        if (MODE == 1) {
          outF[(size_t)m * N + n] = v;
        } else {
          int b = m >> 10, t = m & 1023;
          if (n < 1024) {
            int h = n >> 6, d = n & 63;
            Qd[((size_t)(b * NHEAD + h) * T_SEQ + t) * HDIM + d] = (_Float16)(v * 0.125f);
          } else if (n < 2048) {
            int h = (n - 1024) >> 6, d = n & 63;
            Kd[((size_t)(b * NHEAD + h) * T_SEQ + t) * HDIM + d] = (_Float16)v;
          } else {
            int h = (n - 2048) >> 6, d = n & 63;
            Vtd[((size_t)(b * NHEAD + h) * HDIM + d) * T_SEQ + t] = (_Float16)v;
          }
        }
      }
    }
  }
}

// ------- flash attention: 128 q-rows/block (8 waves), 64-key tiles, async staging -------
__global__ __launch_bounds__(512) void attn_kernel(const _Float16* __restrict__ Kq,
                                                   const _Float16* __restrict__ Kk,
                                                   const _Float16* __restrict__ Vt,
                                                   const int* __restrict__ x_lens,
                                                   _Float16* __restrict__ att) {
  __shared__ _Float16 Ks[2][64 * 32];   // [d-half][key*32 + chunk]
  __shared__ _Float16 Vs[2][64 * 32];   // [key-half][d*32 + chunk]
  __shared__ _Float16 Pb[8][16 * 72];   // per-wave P round-trip (padded; manual writes)
  int blk = blockIdx.x;
  int qt = blk & 7;
  int h  = (blk >> 3) & 15;
  int b  = blk >> 7;
  int t0 = qt * 128;
  int len = x_lens[b];
  int tid = threadIdx.x;
  int wave = tid >> 6, lane = tid & 63;
  int l15 = lane & 15, quad = lane >> 4;
  size_t plane = (size_t)(b * NHEAD + h) * (T_SEQ * HDIM);
  int qrow = t0 + wave * 16;
  const _Float16* Qp = Kq + plane + (size_t)(qrow + l15) * HDIM + quad * 8;
  half8 qf0 = *(const half8*)Qp;
  half8 qf1 = *(const half8*)(Qp + 32);
  v4f zero = {0.f, 0.f, 0.f, 0.f};
  float m_i[4], l_i[4];
  v4f Ov[4];
#pragma unroll
  for (int r = 0; r < 4; ++r) { m_i[r] = -1e30f; l_i[r] = 0.f; }
#pragma unroll
  for (int nt = 0; nt < 4; ++nt) Ov[nt] = zero;

  int jmaxb = min(t0 + 127, len - 1);       // block covers tiles up to here
  int ntile = (jmaxb >> 6) + 1;
  int wjmax = min(qrow + 15, len - 1);      // wave active while j0 <= wjmax

  // staging: 16 wave-units of 1KB; wave w handles units w*2, w*2+1
  // unit u: matrix = u>>3 (0=K,1=V), half = (u>>2)&1, quarter q = u&3
  int u0 = wave * 2;
  const _Float16* src0;
  const _Float16* src1;
  _Float16* dst0;
  _Float16* dst1;
  {
    int u = u0;
    int q = u & 3, hf = (u >> 2) & 1;
    if (u < 8) { // K unit: row j0 + q*16 + (lane>>2), d = hf*32 + (lane&3)*8
      src0 = Kk + plane + (size_t)(q * 16 + (lane >> 2)) * HDIM + hf * 32 + (lane & 3) * 8;
      dst0 = &Ks[hf][0] + q * 512;
    } else {     // V unit: d-row q*16 + (lane>>2), key = j0 + hf*32 + (lane&3)*8
      src0 = Vt + plane + (size_t)(q * 16 + (lane >> 2)) * T_SEQ + hf * 32 + (lane & 3) * 8;
      dst0 = &Vs[hf][0] + q * 512;
    }
    u = u0 + 1;
    q = u & 3; hf = (u >> 2) & 1;
    if (u < 8) {
      src1 = Kk + plane + (size_t)(q * 16 + (lane >> 2)) * HDIM + hf * 32 + (lane & 3) * 8;
      dst1 = &Ks[hf][0] + q * 512;
    } else {
      src1 = Vt + plane + (size_t)(q * 16 + (lane >> 2)) * T_SEQ + hf * 32 + (lane & 3) * 8;
      dst1 = &Vs[hf][0] + q * 512;
    }
  }
  // per-iter advance: K units advance by j0*HDIM elements, V units by j0
  int stride0 = (u0     < 8) ? (64 * HDIM) : 64;
  int stride1 = (u0 + 1 < 8) ? (64 * HDIM) : 64;

  for (int jt = 0; jt < ntile; ++jt) {
    int j0 = jt * 64;
    __syncthreads();
    load_lds16(src0, dst0);
    load_lds16(src1, dst1);
    src0 += stride0;
    src1 += stride1;
    __syncthreads();
    if (j0 <= wjmax) {
      // S = Q K^T  (scale folded into Q)
      v4f s[4];
#pragma unroll
      for (int nt = 0; nt < 4; ++nt) {
        s[nt] = zero;
        half8 k0 = *(const half8*)&Ks[0][(nt * 16 + l15) * 32 + quad * 8];
        half8 k1 = *(const half8*)&Ks[1][(nt * 16 + l15) * 32 + quad * 8];
        s[nt] = __builtin_amdgcn_mfma_f32_16x16x32_f16(qf0, k0, s[nt], 0, 0, 0);
        s[nt] = __builtin_amdgcn_mfma_f32_16x16x32_f16(qf1, k1, s[nt], 0, 0, 0);
      }
      // mask + online softmax (rows = quad*4+r, cols = j0 + nt*16 + l15)
      float rmax[4] = {-1e30f, -1e30f, -1e30f, -1e30f};
#pragma unroll
      for (int nt = 0; nt < 4; ++nt) {
        int col = j0 + nt * 16 + l15;
#pragma unroll
        for (int r = 0; r < 4; ++r) {
          int trow = qrow + quad * 4 + r;
          float v = (col <= trow && col < len) ? s[nt][r] : -1e30f;
          s[nt][r] = v;
          rmax[r] = fmaxf(rmax[r], v);
        }
      }
#pragma unroll
      for (int off = 1; off < 16; off <<= 1)
#pragma unroll
        for (int r = 0; r < 4; ++r)
          rmax[r] = fmaxf(rmax[r], __shfl_xor(rmax[r], off));
      float alpha[4], rsum[4];
#pragma unroll
      for (int r = 0; r < 4; ++r) {
        float mn = fmaxf(m_i[r], rmax[r]);
        alpha[r] = __expf(m_i[r] - mn);
        m_i[r] = mn;
        rsum[r] = 0.f;
      }
#pragma unroll
      for (int nt = 0; nt < 4; ++nt)
#pragma unroll
        for (int r = 0; r < 4; ++r) {
          float p = __expf(s[nt][r] - m_i[r]);
          s[nt][r] = p;
          rsum[r] += p;
        }
#pragma unroll
      for (int off = 1; off < 16; off <<= 1)
#pragma unroll
        for (int r = 0; r < 4; ++r)
          rsum[r] += __shfl_xor(rsum[r], off);
#pragma unroll
      for (int r = 0; r < 4; ++r) l_i[r] = l_i[r] * alpha[r] + rsum[r];
#pragma unroll
      for (int nt = 0; nt < 4; ++nt)
#pragma unroll
        for (int r = 0; r < 4; ++r) Ov[nt][r] *= alpha[r];
      // P: C-layout -> LDS (per-wave buffer) -> A-layout; wave-local sync only
#pragma unroll
      for (int nt = 0; nt < 4; ++nt)
#pragma unroll
        for (int r = 0; r < 4; ++r)
          Pb[wave][(quad * 4 + r) * 72 + nt * 16 + l15] = (_Float16)s[nt][r];
      asm volatile("s_waitcnt lgkmcnt(0)" ::: "memory");
      half8 p0 = *(const half8*)&Pb[wave][l15 * 72 + quad * 8];
      half8 p1 = *(const half8*)&Pb[wave][l15 * 72 + quad * 8 + 32];
#pragma unroll
      for (int nt = 0; nt < 4; ++nt) {
        half8 v0 = *(const half8*)&Vs[0][(nt * 16 + l15) * 32 + quad * 8];
        half8 v1 = *(const half8*)&Vs[1][(nt * 16 + l15) * 32 + quad * 8];
        Ov[nt] = __builtin_amdgcn_mfma_f32_16x16x32_f16(p0, v0, Ov[nt], 0, 0, 0);
        Ov[nt] = __builtin_amdgcn_mfma_f32_16x16x32_f16(p1, v1, Ov[nt], 0, 0, 0);
      }
    }
  }
  float inv[4];
#pragma unroll
  for (int r = 0; r < 4; ++r) inv[r] = 1.0f / l_i[r];
#pragma unroll
  for (int nt = 0; nt < 4; ++nt)
#pragma unroll
    for (int r = 0; r < 4; ++r) {
      int trow = qrow + quad * 4 + r;
      att[((size_t)(b * T_SEQ) + trow) * D_MODEL + h * HDIM + nt * 16 + l15] =
          (_Float16)(Ov[nt][r] * inv[r]);
    }
}

extern "C" void kernel_launch(void* const* d_in, const int* in_sizes, int n_in,
                              void* d_out, int out_size, void* d_ws, size_t ws_size,
                              hipStream_t stream) {
  const float* x        = (const float*)d_in[0];
  const int*   x_lens   = (const int*)d_in[1];
  const float* ln_gamma = (const float*)d_in[2];
  const float* ln_beta  = (const float*)d_in[3];
  const float* w_qkv    = (const float*)d_in[4];
  const float* b_qkv    = (const float*)d_in[5];
  const float* w_out    = (const float*)d_in[6];
  const float* b_out    = (const float*)d_in[7];
  float* out = (float*)d_out;

  char* w = (char*)d_ws;
  _Float16* xn    = (_Float16*)w; w += (size_t)8192 * 1024 * 2;
  _Float16* wqkvT = (_Float16*)w; w += (size_t)3072 * 1024 * 2;
  _Float16* woutT = (_Float16*)w; w += (size_t)1024 * 1024 * 2;
  _Float16* Qd    = (_Float16*)w; w += (size_t)8192 * 1024 * 2;
  _Float16* Kd    = (_Float16*)w; w += (size_t)8192 * 1024 * 2;
  _Float16* Vtd   = (_Float16*)w; w += (size_t)8192 * 1024 * 2;
  _Float16* att   = (_Float16*)w; w += (size_t)8192 * 1024 * 2;

  transpose_kernel<<<dim3(3072 / 32, 1024 / 32), 256, 0, stream>>>(w_qkv, wqkvT, 1024, 3072);
  transpose_kernel<<<dim3(1024 / 32, 1024 / 32), 256, 0, stream>>>(w_out, woutT, 1024, 1024);
  ln_kernel<<<8192, 256, 0, stream>>>(x, ln_gamma, ln_beta, xn);
  gemm_kernel<0><<<dim3(3072 / 128, 8192 / 128), 256, 0, stream>>>(
      xn, wqkvT, b_qkv, 8192, 3072, 1024, nullptr, Qd, Kd, Vtd);
  attn_kernel<<<1024, 512, 0, stream>>>(Qd, Kd, Vtd, x_lens, att);
  gemm_kernel<1><<<dim3(1024 / 128, 8192 / 128), 256, 0, stream>>>(
      att, woutT, b_out, 8192, 1024, 1024, out, nullptr, nullptr, nullptr);
}

// Round 4
// 294.767 us; speedup vs baseline: 1.1011x; 1.0610x over previous
//
#include <hip/hip_runtime.h>

#define D_MODEL 1024
#define T_SEQ   1024
#define BATCH   8
#define NHEAD   16
#define HDIM    64

typedef float      v4f   __attribute__((ext_vector_type(4)));
typedef _Float16   half8 __attribute__((ext_vector_type(8)));
typedef _Float16   half4h __attribute__((ext_vector_type(4)));
typedef unsigned int ui4 __attribute__((ext_vector_type(4)));

// async global->LDS, 16B per lane, dest = wave-uniform base + lane*16
__device__ __forceinline__ void load_lds16(const _Float16* g, _Float16* l) {
  __builtin_amdgcn_global_load_lds(
      (const __attribute__((address_space(1))) unsigned int*)g,
      (__attribute__((address_space(3))) unsigned int*)l, 16, 0, 0);
}

// ---------------- LayerNorm (fp32 in) -> fp16 xn ----------------
__global__ __launch_bounds__(256) void ln_kernel(const float* __restrict__ x,
                                                 const float* __restrict__ gamma,
                                                 const float* __restrict__ beta,
                                                 _Float16* __restrict__ xn) {
  int row = blockIdx.x;
  int tid = threadIdx.x;
  const float* xr = x + (size_t)row * D_MODEL;
  v4f xv = *(const v4f*)(xr + tid * 4);
  float s  = xv[0] + xv[1] + xv[2] + xv[3];
  float sq = xv[0]*xv[0] + xv[1]*xv[1] + xv[2]*xv[2] + xv[3]*xv[3];
#pragma unroll
  for (int off = 32; off > 0; off >>= 1) {
    s  += __shfl_xor(s, off);
    sq += __shfl_xor(sq, off);
  }
  __shared__ float ps[4], psq[4];
  int wave = tid >> 6;
  if ((tid & 63) == 0) { ps[wave] = s; psq[wave] = sq; }
  __syncthreads();
  float tot  = ps[0] + ps[1] + ps[2] + ps[3];
  float totq = psq[0] + psq[1] + psq[2] + psq[3];
  float mean = tot * (1.0f / D_MODEL);
  float var  = totq * (1.0f / D_MODEL) - mean * mean;
  float rs   = rsqrtf(var + 1e-5f);
  v4f gv = *(const v4f*)(gamma + tid * 4);
  v4f bv = *(const v4f*)(beta + tid * 4);
  half4h o;
#pragma unroll
  for (int i = 0; i < 4; ++i)
    o[i] = (_Float16)((xv[i] - mean) * rs * gv[i] + bv[i]);
  *(half4h*)(xn + (size_t)row * D_MODEL + tid * 4) = o;
}

// ------- fragize: W (K x N fp32, row-major) -> Bfrag[nt][kt][lane][8] fp16 -------
// B-fragment for mfma_16x16x32: lane l holds B[n = l&15][k = (l>>4)*8 + j]
__global__ __launch_bounds__(256) void fragize_kernel(const float* __restrict__ W,
                                                      _Float16* __restrict__ Bf,
                                                      int N, int K) {
  int g = blockIdx.x * 256 + threadIdx.x;
  int lane = g & 63, tile = g >> 6;
  int ktiles = K >> 5;
  int kt = tile % ktiles, nt = tile / ktiles;
  int n  = nt * 16 + (lane & 15);
  int k0 = kt * 32 + (lane >> 4) * 8;
  half8 o;
#pragma unroll
  for (int j = 0; j < 8; ++j) o[j] = (_Float16)W[(size_t)(k0 + j) * N + n];
  *(half8*)(Bf + (size_t)g * 8) = o;
}

// ------- batched transpose: Vd (P,1024,64) -> Vt (P,64,1024), fp16 -------
__global__ __launch_bounds__(256) void vtrans_kernel(const _Float16* __restrict__ Vd,
                                                     _Float16* __restrict__ Vt) {
  __shared__ _Float16 tile[64][68];
  int p  = blockIdx.y;
  int t0 = blockIdx.x * 64;
  int tid = threadIdx.x;
  int r = tid >> 3, c = (tid & 7) * 8;
#pragma unroll
  for (int it = 0; it < 2; ++it) {
    int rr = r + it * 32;
    *(ui4*)&tile[rr][c] = *(const ui4*)&Vd[((size_t)p * T_SEQ + t0 + rr) * HDIM + c];
  }
  __syncthreads();
#pragma unroll
  for (int it = 0; it < 2; ++it) {
    int d = r + it * 32;
    half8 o;
#pragma unroll
    for (int j = 0; j < 8; ++j) o[j] = tile[c + j][d];
    *(half8*)&Vt[((size_t)p * HDIM + d) * T_SEQ + t0 + c] = o;
  }
}

// ---------------- 128x128 MFMA GEMM: A staged in LDS, B-frags streamed from L2 ----
// MODE 0: epilogue -> Q(B,H,T,64)*0.125, K(B,H,T,64), V(B,H,T,64)
// MODE 1: epilogue -> fp32 out + bias
template <int MODE>
__global__ __launch_bounds__(256) void gemm_kernel(
    const _Float16* __restrict__ A, const _Float16* __restrict__ Bfrag,
    const float* __restrict__ bias, int M, int N, int K,
    float* __restrict__ outF,
    _Float16* __restrict__ Qd, _Float16* __restrict__ Kd, _Float16* __restrict__ Vd) {
  __shared__ _Float16 As[128 * 32];   // 8 KB: A only
  int tid = threadIdx.x;
  int wave = tid >> 6, lane = tid & 63;
  int l15 = lane & 15, quad = lane >> 4;
  int wm = (wave & 1) * 64, wn = (wave >> 1) * 64;
  int m0 = blockIdx.x * 128, n0 = blockIdx.y * 128;   // x = M-dim: residents share B
  v4f zero = {0.f, 0.f, 0.f, 0.f};
  v4f acc[4][4];
#pragma unroll
  for (int i = 0; i < 4; ++i)
#pragma unroll
    for (int j = 0; j < 4; ++j) acc[i][j] = zero;

  int ar0 = tid >> 2;          // per-block row 0..63 (chunk 1: +64)
  int akc = (tid & 3) * 8;
  const _Float16* Ap = A + (size_t)(m0 + ar0) * K + akc;
  _Float16* AsW = As + wave * 512;            // lane L lands at +L*16B
  const int ktiles = K >> 5;
  const _Float16* Bp = Bfrag + (size_t)((n0 + wn) >> 4) * ktiles * 512 + lane * 8;

  for (int kt = 0; kt < ktiles; ++kt) {
    // B-fragments direct from global (L2): 4 x 1KB contiguous per wave
    half8 bf[4];
#pragma unroll
    for (int ni = 0; ni < 4; ++ni)
      bf[ni] = *(const half8*)(Bp + ((size_t)ni * ktiles + kt) * 512);
    __syncthreads();
    load_lds16(Ap + kt * 32,                  AsW);
    load_lds16(Ap + kt * 32 + (size_t)64 * K, AsW + 2048);
    __syncthreads();
    half8 af[4];
#pragma unroll
    for (int i = 0; i < 4; ++i)
      af[i] = *(const half8*)&As[(wm + i * 16 + l15) * 32 + quad * 8];
#pragma unroll
    for (int mi = 0; mi < 4; ++mi)
#pragma unroll
      for (int ni = 0; ni < 4; ++ni)
        acc[mi][ni] = __builtin_amdgcn_mfma_f32_16x16x32_f16(af[mi], bf[ni], acc[mi][ni], 0, 0, 0);
  }
  // epilogue: C layout row=quad*4+r, col=l15
  float bv[4];
#pragma unroll
  for (int ni = 0; ni < 4; ++ni) bv[ni] = bias[n0 + wn + ni * 16 + l15];
#pragma unroll
  for (int mi = 0; mi < 4; ++mi) {
#pragma unroll
    for (int ni = 0; ni < 4; ++ni) {
      int n = n0 + wn + ni * 16 + l15;
#pragma unroll
      for (int r = 0; r < 4; ++r) {
        int m = m0 + wm + mi * 16 + quad * 4 + r;
        float v = acc[mi][ni][r] + bv[ni];
        if (MODE == 1) {
          outF[(size_t)m * N + n] = v;
        } else {
          int b = m >> 10, t = m & 1023;
          int h = (n >> 6) & 15, d = n & 63;
          size_t idx = ((size_t)(b * NHEAD + h) * T_SEQ + t) * HDIM + d;
          if (n < 1024)        Qd[idx] = (_Float16)(v * 0.125f);
          else if (n < 2048)   Kd[idx] = (_Float16)v;
          else                 Vd[idx] = (_Float16)v;
        }
      }
    }
  }
}

// ------- flash attention: 128 q-rows/block (8 waves), 64-key tiles, async staging -------
__global__ __launch_bounds__(512) void attn_kernel(const _Float16* __restrict__ Kq,
                                                   const _Float16* __restrict__ Kk,
                                                   const _Float16* __restrict__ Vt,
                                                   const int* __restrict__ x_lens,
                                                   _Float16* __restrict__ att) {
  __shared__ _Float16 Ks[2][64 * 32];   // [d-half][key*32 + chunk]
  __shared__ _Float16 Vs[2][64 * 32];   // [key-half][d*32 + chunk]
  __shared__ _Float16 Pb[8][16 * 72];   // per-wave P round-trip
  int blk = blockIdx.x;
  int qt = blk & 7;
  int h  = (blk >> 3) & 15;
  int b  = blk >> 7;
  int t0 = qt * 128;
  int len = x_lens[b];
  int tid = threadIdx.x;
  int wave = tid >> 6, lane = tid & 63;
  int l15 = lane & 15, quad = lane >> 4;
  size_t plane = (size_t)(b * NHEAD + h) * (T_SEQ * HDIM);
  int qrow = t0 + wave * 16;
  const _Float16* Qp = Kq + plane + (size_t)(qrow + l15) * HDIM + quad * 8;
  half8 qf0 = *(const half8*)Qp;
  half8 qf1 = *(const half8*)(Qp + 32);
  v4f zero = {0.f, 0.f, 0.f, 0.f};
  float m_i[4], l_i[4];
  v4f Ov[4];
#pragma unroll
  for (int r = 0; r < 4; ++r) { m_i[r] = -1e30f; l_i[r] = 0.f; }
#pragma unroll
  for (int nt = 0; nt < 4; ++nt) Ov[nt] = zero;

  int jmaxb = min(t0 + 127, len - 1);
  int ntile = (jmaxb >> 6) + 1;
  int wjmax = min(qrow + 15, len - 1);

  int u0 = wave * 2;
  const _Float16* src0;
  const _Float16* src1;
  _Float16* dst0;
  _Float16* dst1;
  {
    int u = u0;
    int q = u & 3, hf = (u >> 2) & 1;
    if (u < 8) {
      src0 = Kk + plane + (size_t)(q * 16 + (lane >> 2)) * HDIM + hf * 32 + (lane & 3) * 8;
      dst0 = &Ks[hf][0] + q * 512;
    } else {
      src0 = Vt + plane + (size_t)(q * 16 + (lane >> 2)) * T_SEQ + hf * 32 + (lane & 3) * 8;
      dst0 = &Vs[hf][0] + q * 512;
    }
    u = u0 + 1;
    q = u & 3; hf = (u >> 2) & 1;
    if (u < 8) {
      src1 = Kk + plane + (size_t)(q * 16 + (lane >> 2)) * HDIM + hf * 32 + (lane & 3) * 8;
      dst1 = &Ks[hf][0] + q * 512;
    } else {
      src1 = Vt + plane + (size_t)(q * 16 + (lane >> 2)) * T_SEQ + hf * 32 + (lane & 3) * 8;
      dst1 = &Vs[hf][0] + q * 512;
    }
  }
  int stride0 = (u0     < 8) ? (64 * HDIM) : 64;
  int stride1 = (u0 + 1 < 8) ? (64 * HDIM) : 64;

  for (int jt = 0; jt < ntile; ++jt) {
    int j0 = jt * 64;
    __syncthreads();
    load_lds16(src0, dst0);
    load_lds16(src1, dst1);
    src0 += stride0;
    src1 += stride1;
    __syncthreads();
    if (j0 <= wjmax) {
      v4f s[4];
#pragma unroll
      for (int nt = 0; nt < 4; ++nt) {
        s[nt] = zero;
        half8 k0 = *(const half8*)&Ks[0][(nt * 16 + l15) * 32 + quad * 8];
        half8 k1 = *(const half8*)&Ks[1][(nt * 16 + l15) * 32 + quad * 8];
        s[nt] = __builtin_amdgcn_mfma_f32_16x16x32_f16(qf0, k0, s[nt], 0, 0, 0);
        s[nt] = __builtin_amdgcn_mfma_f32_16x16x32_f16(qf1, k1, s[nt], 0, 0, 0);
      }
      float rmax[4] = {-1e30f, -1e30f, -1e30f, -1e30f};
#pragma unroll
      for (int nt = 0; nt < 4; ++nt) {
        int col = j0 + nt * 16 + l15;
#pragma unroll
        for (int r = 0; r < 4; ++r) {
          int trow = qrow + quad * 4 + r;
          float v = (col <= trow && col < len) ? s[nt][r] : -1e30f;
          s[nt][r] = v;
          rmax[r] = fmaxf(rmax[r], v);
        }
      }
#pragma unroll
      for (int off = 1; off < 16; off <<= 1)
#pragma unroll
        for (int r = 0; r < 4; ++r)
          rmax[r] = fmaxf(rmax[r], __shfl_xor(rmax[r], off));
      float alpha[4], rsum[4];
#pragma unroll
      for (int r = 0; r < 4; ++r) {
        float mn = fmaxf(m_i[r], rmax[r]);
        alpha[r] = __expf(m_i[r] - mn);
        m_i[r] = mn;
        rsum[r] = 0.f;
      }
#pragma unroll
      for (int nt = 0; nt < 4; ++nt)
#pragma unroll
        for (int r = 0; r < 4; ++r) {
          float p = __expf(s[nt][r] - m_i[r]);
          s[nt][r] = p;
          rsum[r] += p;
        }
#pragma unroll
      for (int off = 1; off < 16; off <<= 1)
#pragma unroll
        for (int r = 0; r < 4; ++r)
          rsum[r] += __shfl_xor(rsum[r], off);
#pragma unroll
      for (int r = 0; r < 4; ++r) l_i[r] = l_i[r] * alpha[r] + rsum[r];
#pragma unroll
      for (int nt = 0; nt < 4; ++nt)
#pragma unroll
        for (int r = 0; r < 4; ++r) Ov[nt][r] *= alpha[r];
#pragma unroll
      for (int nt = 0; nt < 4; ++nt)
#pragma unroll
        for (int r = 0; r < 4; ++r)
          Pb[wave][(quad * 4 + r) * 72 + nt * 16 + l15] = (_Float16)s[nt][r];
      asm volatile("s_waitcnt lgkmcnt(0)" ::: "memory");
      half8 p0 = *(const half8*)&Pb[wave][l15 * 72 + quad * 8];
      half8 p1 = *(const half8*)&Pb[wave][l15 * 72 + quad * 8 + 32];
#pragma unroll
      for (int nt = 0; nt < 4; ++nt) {
        half8 v0 = *(const half8*)&Vs[0][(nt * 16 + l15) * 32 + quad * 8];
        half8 v1 = *(const half8*)&Vs[1][(nt * 16 + l15) * 32 + quad * 8];
        Ov[nt] = __builtin_amdgcn_mfma_f32_16x16x32_f16(p0, v0, Ov[nt], 0, 0, 0);
        Ov[nt] = __builtin_amdgcn_mfma_f32_16x16x32_f16(p1, v1, Ov[nt], 0, 0, 0);
      }
    }
  }
  float inv[4];
#pragma unroll
  for (int r = 0; r < 4; ++r) inv[r] = 1.0f / l_i[r];
#pragma unroll
  for (int nt = 0; nt < 4; ++nt)
#pragma unroll
    for (int r = 0; r < 4; ++r) {
      int trow = qrow + quad * 4 + r;
      att[((size_t)(b * T_SEQ) + trow) * D_MODEL + h * HDIM + nt * 16 + l15] =
          (_Float16)(Ov[nt][r] * inv[r]);
    }
}

extern "C" void kernel_launch(void* const* d_in, const int* in_sizes, int n_in,
                              void* d_out, int out_size, void* d_ws, size_t ws_size,
                              hipStream_t stream) {
  const float* x        = (const float*)d_in[0];
  const int*   x_lens   = (const int*)d_in[1];
  const float* ln_gamma = (const float*)d_in[2];
  const float* ln_beta  = (const float*)d_in[3];
  const float* w_qkv    = (const float*)d_in[4];
  const float* b_qkv    = (const float*)d_in[5];
  const float* w_out    = (const float*)d_in[6];
  const float* b_out    = (const float*)d_in[7];
  float* out = (float*)d_out;

  char* w = (char*)d_ws;
  _Float16* xn    = (_Float16*)w; w += (size_t)8192 * 1024 * 2;   // 16MB (aliased by Vt later)
  _Float16* BfQKV = (_Float16*)w; w += (size_t)3072 * 1024 * 2;   // 6MB
  _Float16* BfOut = (_Float16*)w; w += (size_t)1024 * 1024 * 2;   // 2MB
  _Float16* Qd    = (_Float16*)w; w += (size_t)8192 * 1024 * 2;
  _Float16* Kd    = (_Float16*)w; w += (size_t)8192 * 1024 * 2;
  _Float16* Vd    = (_Float16*)w; w += (size_t)8192 * 1024 * 2;
  _Float16* att   = (_Float16*)w; w += (size_t)8192 * 1024 * 2;
  _Float16* Vt    = xn;   // xn dead after gemm<0>; reuse for V^T

  fragize_kernel<<<(3072 * 1024 / 8) / 256, 256, 0, stream>>>(w_qkv, BfQKV, 3072, 1024);
  fragize_kernel<<<(1024 * 1024 / 8) / 256, 256, 0, stream>>>(w_out, BfOut, 1024, 1024);
  ln_kernel<<<8192, 256, 0, stream>>>(x, ln_gamma, ln_beta, xn);
  gemm_kernel<0><<<dim3(8192 / 128, 3072 / 128), 256, 0, stream>>>(
      xn, BfQKV, b_qkv, 8192, 3072, 1024, nullptr, Qd, Kd, Vd);
  vtrans_kernel<<<dim3(16, 128), 256, 0, stream>>>(Vd, Vt);
  attn_kernel<<<1024, 512, 0, stream>>>(Qd, Kd, Vt, x_lens, att);
  gemm_kernel<1><<<dim3(8192 / 128, 1024 / 128), 256, 0, stream>>>(
      att, BfOut, b_out, 8192, 1024, 1024, out, nullptr, nullptr, nullptr);
}

// Round 5
// 282.927 us; speedup vs baseline: 1.1471x; 1.0419x over previous
//
#include <hip/hip_runtime.h>

#define D_MODEL 1024
#define T_SEQ   1024
#define BATCH   8
#define NHEAD   16
#define HDIM    64

typedef float      v4f   __attribute__((ext_vector_type(4)));
typedef _Float16   half8 __attribute__((ext_vector_type(8)));
typedef _Float16   half4h __attribute__((ext_vector_type(4)));
typedef unsigned int ui4 __attribute__((ext_vector_type(4)));

// async global->LDS, 16B per lane, dest = wave-uniform base + lane*16
__device__ __forceinline__ void load_lds16(const _Float16* g, _Float16* l) {
  __builtin_amdgcn_global_load_lds(
      (const __attribute__((address_space(1))) unsigned int*)g,
      (__attribute__((address_space(3))) unsigned int*)l, 16, 0, 0);
}

// ---------------- LayerNorm (fp32 in) -> fp16 xn ----------------
__global__ __launch_bounds__(256) void ln_kernel(const float* __restrict__ x,
                                                 const float* __restrict__ gamma,
                                                 const float* __restrict__ beta,
                                                 _Float16* __restrict__ xn) {
  int row = blockIdx.x;
  int tid = threadIdx.x;
  const float* xr = x + (size_t)row * D_MODEL;
  v4f xv = *(const v4f*)(xr + tid * 4);
  float s  = xv[0] + xv[1] + xv[2] + xv[3];
  float sq = xv[0]*xv[0] + xv[1]*xv[1] + xv[2]*xv[2] + xv[3]*xv[3];
#pragma unroll
  for (int off = 32; off > 0; off >>= 1) {
    s  += __shfl_xor(s, off);
    sq += __shfl_xor(sq, off);
  }
  __shared__ float ps[4], psq[4];
  int wave = tid >> 6;
  if ((tid & 63) == 0) { ps[wave] = s; psq[wave] = sq; }
  __syncthreads();
  float tot  = ps[0] + ps[1] + ps[2] + ps[3];
  float totq = psq[0] + psq[1] + psq[2] + psq[3];
  float mean = tot * (1.0f / D_MODEL);
  float var  = totq * (1.0f / D_MODEL) - mean * mean;
  float rs   = rsqrtf(var + 1e-5f);
  v4f gv = *(const v4f*)(gamma + tid * 4);
  v4f bv = *(const v4f*)(beta + tid * 4);
  half4h o;
#pragma unroll
  for (int i = 0; i < 4; ++i)
    o[i] = (_Float16)((xv[i] - mean) * rs * gv[i] + bv[i]);
  *(half4h*)(xn + (size_t)row * D_MODEL + tid * 4) = o;
}

// ------- fragize: W (K x N fp32, row-major) -> Bfrag[nt][kt][lane][8] fp16 -------
__global__ __launch_bounds__(256) void fragize_kernel(const float* __restrict__ W,
                                                      _Float16* __restrict__ Bf,
                                                      int N, int K) {
  int g = blockIdx.x * 256 + threadIdx.x;
  int lane = g & 63, tile = g >> 6;
  int ktiles = K >> 5;
  int kt = tile % ktiles, nt = tile / ktiles;
  int n  = nt * 16 + (lane & 15);
  int k0 = kt * 32 + (lane >> 4) * 8;
  half8 o;
#pragma unroll
  for (int j = 0; j < 8; ++j) o[j] = (_Float16)W[(size_t)(k0 + j) * N + n];
  *(half8*)(Bf + (size_t)g * 8) = o;
}

// ------- batched transpose: Vd (P,1024,64) -> Vt (P,64,1024), fp16 -------
__global__ __launch_bounds__(256) void vtrans_kernel(const _Float16* __restrict__ Vd,
                                                     _Float16* __restrict__ Vt) {
  __shared__ _Float16 tile[64][68];
  int p  = blockIdx.y;
  int t0 = blockIdx.x * 64;
  int tid = threadIdx.x;
  int r = tid >> 3, c = (tid & 7) * 8;
#pragma unroll
  for (int it = 0; it < 2; ++it) {
    int rr = r + it * 32;
    *(ui4*)&tile[rr][c] = *(const ui4*)&Vd[((size_t)p * T_SEQ + t0 + rr) * HDIM + c];
  }
  __syncthreads();
#pragma unroll
  for (int it = 0; it < 2; ++it) {
    int d = r + it * 32;
    half8 o;
#pragma unroll
    for (int j = 0; j < 8; ++j) o[j] = tile[c + j][d];
    *(half8*)&Vt[((size_t)p * HDIM + d) * T_SEQ + t0 + c] = o;
  }
}

// ---------------- 128x128 MFMA GEMM: A staged in LDS, B-frags streamed from L2 ----
// MODE 0: epilogue -> Q(B,H,T,64)*(0.125*log2e), K(B,H,T,64), V(B,H,T,64)
// MODE 1: epilogue -> fp32 out + bias
template <int MODE>
__global__ __launch_bounds__(256) void gemm_kernel(
    const _Float16* __restrict__ A, const _Float16* __restrict__ Bfrag,
    const float* __restrict__ bias, int M, int N, int K,
    float* __restrict__ outF,
    _Float16* __restrict__ Qd, _Float16* __restrict__ Kd, _Float16* __restrict__ Vd) {
  __shared__ _Float16 As[128 * 32];   // 8 KB: A only
  int tid = threadIdx.x;
  int wave = tid >> 6, lane = tid & 63;
  int l15 = lane & 15, quad = lane >> 4;
  int wm = (wave & 1) * 64, wn = (wave >> 1) * 64;
  int m0 = blockIdx.x * 128, n0 = blockIdx.y * 128;   // x = M-dim: residents share B
  v4f zero = {0.f, 0.f, 0.f, 0.f};
  v4f acc[4][4];
#pragma unroll
  for (int i = 0; i < 4; ++i)
#pragma unroll
    for (int j = 0; j < 4; ++j) acc[i][j] = zero;

  int ar0 = tid >> 2;          // per-block row 0..63 (chunk 1: +64)
  int akc = (tid & 3) * 8;
  const _Float16* Ap = A + (size_t)(m0 + ar0) * K + akc;
  _Float16* AsW = As + wave * 512;            // lane L lands at +L*16B
  const int ktiles = K >> 5;
  const _Float16* Bp = Bfrag + (size_t)((n0 + wn) >> 4) * ktiles * 512 + lane * 8;

  for (int kt = 0; kt < ktiles; ++kt) {
    half8 bf[4];
#pragma unroll
    for (int ni = 0; ni < 4; ++ni)
      bf[ni] = *(const half8*)(Bp + ((size_t)ni * ktiles + kt) * 512);
    __syncthreads();
    load_lds16(Ap + kt * 32,                  AsW);
    load_lds16(Ap + kt * 32 + (size_t)64 * K, AsW + 2048);
    __syncthreads();
    half8 af[4];
#pragma unroll
    for (int i = 0; i < 4; ++i)
      af[i] = *(const half8*)&As[(wm + i * 16 + l15) * 32 + quad * 8];
#pragma unroll
    for (int mi = 0; mi < 4; ++mi)
#pragma unroll
      for (int ni = 0; ni < 4; ++ni)
        acc[mi][ni] = __builtin_amdgcn_mfma_f32_16x16x32_f16(af[mi], bf[ni], acc[mi][ni], 0, 0, 0);
  }
  // epilogue: C layout row=quad*4+r, col=l15
  float bv[4];
#pragma unroll
  for (int ni = 0; ni < 4; ++ni) bv[ni] = bias[n0 + wn + ni * 16 + l15];
#pragma unroll
  for (int mi = 0; mi < 4; ++mi) {
#pragma unroll
    for (int ni = 0; ni < 4; ++ni) {
      int n = n0 + wn + ni * 16 + l15;
#pragma unroll
      for (int r = 0; r < 4; ++r) {
        int m = m0 + wm + mi * 16 + quad * 4 + r;
        float v = acc[mi][ni][r] + bv[ni];
        if (MODE == 1) {
          outF[(size_t)m * N + n] = v;
        } else {
          int b = m >> 10, t = m & 1023;
          int h = (n >> 6) & 15, d = n & 63;
          size_t idx = ((size_t)(b * NHEAD + h) * T_SEQ + t) * HDIM + d;
          // 0.125 * log2(e): softmax runs in exp2 domain
          if (n < 1024)        Qd[idx] = (_Float16)(v * 0.18033688f);
          else if (n < 2048)   Kd[idx] = (_Float16)v;
          else                 Vd[idx] = (_Float16)v;
        }
      }
    }
  }
}

// ------- flash attention: 128 q-rows/block (8 waves), 64-key tiles, async staging -------
__global__ __launch_bounds__(512) void attn_kernel(const _Float16* __restrict__ Kq,
                                                   const _Float16* __restrict__ Kk,
                                                   const _Float16* __restrict__ Vt,
                                                   const int* __restrict__ x_lens,
                                                   _Float16* __restrict__ att) {
  __shared__ _Float16 Ks[2][64 * 32];   // [d-half][key*32 + chunk]
  __shared__ _Float16 Vs[2][64 * 32];   // [key-half][d*32 + chunk]
  __shared__ _Float16 Pb[8][16 * 72];   // per-wave P round-trip
  int blk = blockIdx.x;
  int qt = blk >> 7;          // high bits: balances per-CU work (qt mix per CU)
  int bh = blk & 127;
  int h  = bh & 15;
  int b  = bh >> 4;
  int t0 = qt * 128;
  int len = x_lens[b];
  int tid = threadIdx.x;
  int wave = tid >> 6, lane = tid & 63;
  int l15 = lane & 15, quad = lane >> 4;
  size_t plane = (size_t)(b * NHEAD + h) * (T_SEQ * HDIM);
  int qrow = t0 + wave * 16;
  const _Float16* Qp = Kq + plane + (size_t)(qrow + l15) * HDIM + quad * 8;
  half8 qf0 = *(const half8*)Qp;
  half8 qf1 = *(const half8*)(Qp + 32);
  v4f zero = {0.f, 0.f, 0.f, 0.f};
  float m_i[4], l_i[4];
  v4f Ov[4];
#pragma unroll
  for (int r = 0; r < 4; ++r) { m_i[r] = -1e30f; l_i[r] = 0.f; }
#pragma unroll
  for (int nt = 0; nt < 4; ++nt) Ov[nt] = zero;

  int jmaxb = min(t0 + 127, len - 1);
  int ntile = (jmaxb >> 6) + 1;
  int wjmax = min(qrow + 15, len - 1);

  int u0 = wave * 2;
  const _Float16* src0;
  const _Float16* src1;
  _Float16* dst0;
  _Float16* dst1;
  {
    int u = u0;
    int q = u & 3, hf = (u >> 2) & 1;
    if (u < 8) {
      src0 = Kk + plane + (size_t)(q * 16 + (lane >> 2)) * HDIM + hf * 32 + (lane & 3) * 8;
      dst0 = &Ks[hf][0] + q * 512;
    } else {
      src0 = Vt + plane + (size_t)(q * 16 + (lane >> 2)) * T_SEQ + hf * 32 + (lane & 3) * 8;
      dst0 = &Vs[hf][0] + q * 512;
    }
    u = u0 + 1;
    q = u & 3; hf = (u >> 2) & 1;
    if (u < 8) {
      src1 = Kk + plane + (size_t)(q * 16 + (lane >> 2)) * HDIM + hf * 32 + (lane & 3) * 8;
      dst1 = &Ks[hf][0] + q * 512;
    } else {
      src1 = Vt + plane + (size_t)(q * 16 + (lane >> 2)) * T_SEQ + hf * 32 + (lane & 3) * 8;
      dst1 = &Vs[hf][0] + q * 512;
    }
  }
  int stride0 = (u0     < 8) ? (64 * HDIM) : 64;
  int stride1 = (u0 + 1 < 8) ? (64 * HDIM) : 64;

  for (int jt = 0; jt < ntile; ++jt) {
    int j0 = jt * 64;
    __syncthreads();
    load_lds16(src0, dst0);
    load_lds16(src1, dst1);
    src0 += stride0;
    src1 += stride1;
    __syncthreads();
    if (j0 <= wjmax) {
      v4f s[4];
#pragma unroll
      for (int nt = 0; nt < 4; ++nt) {
        s[nt] = zero;
        half8 k0 = *(const half8*)&Ks[0][(nt * 16 + l15) * 32 + quad * 8];
        half8 k1 = *(const half8*)&Ks[1][(nt * 16 + l15) * 32 + quad * 8];
        s[nt] = __builtin_amdgcn_mfma_f32_16x16x32_f16(qf0, k0, s[nt], 0, 0, 0);
        s[nt] = __builtin_amdgcn_mfma_f32_16x16x32_f16(qf1, k1, s[nt], 0, 0, 0);
      }
      float rmax[4] = {-1e30f, -1e30f, -1e30f, -1e30f};
      bool full = (j0 + 63 <= qrow) && (j0 + 63 < len);   // wave-uniform fast path
      if (full) {
#pragma unroll
        for (int nt = 0; nt < 4; ++nt)
#pragma unroll
          for (int r = 0; r < 4; ++r)
            rmax[r] = fmaxf(rmax[r], s[nt][r]);
      } else {
#pragma unroll
        for (int nt = 0; nt < 4; ++nt) {
          int col = j0 + nt * 16 + l15;
#pragma unroll
          for (int r = 0; r < 4; ++r) {
            int trow = qrow + quad * 4 + r;
            float v = (col <= trow && col < len) ? s[nt][r] : -1e30f;
            s[nt][r] = v;
            rmax[r] = fmaxf(rmax[r], v);
          }
        }
      }
#pragma unroll
      for (int off = 1; off < 16; off <<= 1)
#pragma unroll
        for (int r = 0; r < 4; ++r)
          rmax[r] = fmaxf(rmax[r], __shfl_xor(rmax[r], off));
      float alpha[4], rsum[4];
#pragma unroll
      for (int r = 0; r < 4; ++r) {
        float mn = fmaxf(m_i[r], rmax[r]);
        alpha[r] = exp2f(m_i[r] - mn);
        m_i[r] = mn;
        rsum[r] = 0.f;
      }
#pragma unroll
      for (int nt = 0; nt < 4; ++nt)
#pragma unroll
        for (int r = 0; r < 4; ++r) {
          float p = exp2f(s[nt][r] - m_i[r]);
          s[nt][r] = p;
          rsum[r] += p;
        }
#pragma unroll
      for (int off = 1; off < 16; off <<= 1)
#pragma unroll
        for (int r = 0; r < 4; ++r)
          rsum[r] += __shfl_xor(rsum[r], off);
#pragma unroll
      for (int r = 0; r < 4; ++r) l_i[r] = l_i[r] * alpha[r] + rsum[r];
#pragma unroll
      for (int nt = 0; nt < 4; ++nt)
#pragma unroll
        for (int r = 0; r < 4; ++r) Ov[nt][r] *= alpha[r];
#pragma unroll
      for (int nt = 0; nt < 4; ++nt)
#pragma unroll
        for (int r = 0; r < 4; ++r)
          Pb[wave][(quad * 4 + r) * 72 + nt * 16 + l15] = (_Float16)s[nt][r];
      asm volatile("s_waitcnt lgkmcnt(0)" ::: "memory");
      half8 p0 = *(const half8*)&Pb[wave][l15 * 72 + quad * 8];
      half8 p1 = *(const half8*)&Pb[wave][l15 * 72 + quad * 8 + 32];
#pragma unroll
      for (int nt = 0; nt < 4; ++nt) {
        half8 v0 = *(const half8*)&Vs[0][(nt * 16 + l15) * 32 + quad * 8];
        half8 v1 = *(const half8*)&Vs[1][(nt * 16 + l15) * 32 + quad * 8];
        Ov[nt] = __builtin_amdgcn_mfma_f32_16x16x32_f16(p0, v0, Ov[nt], 0, 0, 0);
        Ov[nt] = __builtin_amdgcn_mfma_f32_16x16x32_f16(p1, v1, Ov[nt], 0, 0, 0);
      }
    }
  }
  float inv[4];
#pragma unroll
  for (int r = 0; r < 4; ++r) inv[r] = 1.0f / l_i[r];
#pragma unroll
  for (int nt = 0; nt < 4; ++nt)
#pragma unroll
    for (int r = 0; r < 4; ++r) {
      int trow = qrow + quad * 4 + r;
      att[((size_t)(b * T_SEQ) + trow) * D_MODEL + h * HDIM + nt * 16 + l15] =
          (_Float16)(Ov[nt][r] * inv[r]);
    }
}

extern "C" void kernel_launch(void* const* d_in, const int* in_sizes, int n_in,
                              void* d_out, int out_size, void* d_ws, size_t ws_size,
                              hipStream_t stream) {
  const float* x        = (const float*)d_in[0];
  const int*   x_lens   = (const int*)d_in[1];
  const float* ln_gamma = (const float*)d_in[2];
  const float* ln_beta  = (const float*)d_in[3];
  const float* w_qkv    = (const float*)d_in[4];
  const float* b_qkv    = (const float*)d_in[5];
  const float* w_out    = (const float*)d_in[6];
  const float* b_out    = (const float*)d_in[7];
  float* out = (float*)d_out;

  char* w = (char*)d_ws;
  _Float16* xn    = (_Float16*)w; w += (size_t)8192 * 1024 * 2;   // 16MB (aliased by Vt later)
  _Float16* BfQKV = (_Float16*)w; w += (size_t)3072 * 1024 * 2;   // 6MB
  _Float16* BfOut = (_Float16*)w; w += (size_t)1024 * 1024 * 2;   // 2MB
  _Float16* Qd    = (_Float16*)w; w += (size_t)8192 * 1024 * 2;
  _Float16* Kd    = (_Float16*)w; w += (size_t)8192 * 1024 * 2;
  _Float16* Vd    = (_Float16*)w; w += (size_t)8192 * 1024 * 2;
  _Float16* att   = (_Float16*)w; w += (size_t)8192 * 1024 * 2;
  _Float16* Vt    = xn;   // xn dead after gemm<0>; reuse for V^T

  fragize_kernel<<<(3072 * 1024 / 8) / 256, 256, 0, stream>>>(w_qkv, BfQKV, 3072, 1024);
  fragize_kernel<<<(1024 * 1024 / 8) / 256, 256, 0, stream>>>(w_out, BfOut, 1024, 1024);
  ln_kernel<<<8192, 256, 0, stream>>>(x, ln_gamma, ln_beta, xn);
  gemm_kernel<0><<<dim3(8192 / 128, 3072 / 128), 256, 0, stream>>>(
      xn, BfQKV, b_qkv, 8192, 3072, 1024, nullptr, Qd, Kd, Vd);
  vtrans_kernel<<<dim3(16, 128), 256, 0, stream>>>(Vd, Vt);
  attn_kernel<<<1024, 512, 0, stream>>>(Qd, Kd, Vt, x_lens, att);
  gemm_kernel<1><<<dim3(8192 / 128, 1024 / 128), 256, 0, stream>>>(
      att, BfOut, b_out, 8192, 1024, 1024, out, nullptr, nullptr, nullptr);
}

// Round 6
// 263.965 us; speedup vs baseline: 1.2296x; 1.0718x over previous
//
#include <hip/hip_runtime.h>

#define D_MODEL 1024
#define T_SEQ   1024
#define BATCH   8
#define NHEAD   16
#define HDIM    64

typedef float      v4f   __attribute__((ext_vector_type(4)));
typedef _Float16   half8 __attribute__((ext_vector_type(8)));
typedef _Float16   half4h __attribute__((ext_vector_type(4)));
typedef unsigned int ui4 __attribute__((ext_vector_type(4)));

// async global->LDS, 16B per lane, dest = wave-uniform base + lane*16
__device__ __forceinline__ void load_lds16(const _Float16* g, _Float16* l) {
  __builtin_amdgcn_global_load_lds(
      (const __attribute__((address_space(1))) unsigned int*)g,
      (__attribute__((address_space(3))) unsigned int*)l, 16, 0, 0);
}

// ---------------- LayerNorm (fp32 in) -> fp16 xn ----------------
__global__ __launch_bounds__(256) void ln_kernel(const float* __restrict__ x,
                                                 const float* __restrict__ gamma,
                                                 const float* __restrict__ beta,
                                                 _Float16* __restrict__ xn) {
  int row = blockIdx.x;
  int tid = threadIdx.x;
  const float* xr = x + (size_t)row * D_MODEL;
  v4f xv = *(const v4f*)(xr + tid * 4);
  float s  = xv[0] + xv[1] + xv[2] + xv[3];
  float sq = xv[0]*xv[0] + xv[1]*xv[1] + xv[2]*xv[2] + xv[3]*xv[3];
#pragma unroll
  for (int off = 32; off > 0; off >>= 1) {
    s  += __shfl_xor(s, off);
    sq += __shfl_xor(sq, off);
  }
  __shared__ float ps[4], psq[4];
  int wave = tid >> 6;
  if ((tid & 63) == 0) { ps[wave] = s; psq[wave] = sq; }
  __syncthreads();
  float tot  = ps[0] + ps[1] + ps[2] + ps[3];
  float totq = psq[0] + psq[1] + psq[2] + psq[3];
  float mean = tot * (1.0f / D_MODEL);
  float var  = totq * (1.0f / D_MODEL) - mean * mean;
  float rs   = rsqrtf(var + 1e-5f);
  v4f gv = *(const v4f*)(gamma + tid * 4);
  v4f bv = *(const v4f*)(beta + tid * 4);
  half4h o;
#pragma unroll
  for (int i = 0; i < 4; ++i)
    o[i] = (_Float16)((xv[i] - mean) * rs * gv[i] + bv[i]);
  *(half4h*)(xn + (size_t)row * D_MODEL + tid * 4) = o;
}

// ------- fragize: W (K x N fp32, row-major) -> Bfrag[nt][kt][lane][8] fp16 -------
__global__ __launch_bounds__(256) void fragize_kernel(const float* __restrict__ W,
                                                      _Float16* __restrict__ Bf,
                                                      int N, int K) {
  int g = blockIdx.x * 256 + threadIdx.x;
  int lane = g & 63, tile = g >> 6;
  int ktiles = K >> 5;
  int kt = tile % ktiles, nt = tile / ktiles;
  int n  = nt * 16 + (lane & 15);
  int k0 = kt * 32 + (lane >> 4) * 8;
  half8 o;
#pragma unroll
  for (int j = 0; j < 8; ++j) o[j] = (_Float16)W[(size_t)(k0 + j) * N + n];
  *(half8*)(Bf + (size_t)g * 8) = o;
}

// ------- batched transpose: Vd (P,1024,64) -> Vt (P,64,1024), fp16 -------
__global__ __launch_bounds__(256) void vtrans_kernel(const _Float16* __restrict__ Vd,
                                                     _Float16* __restrict__ Vt) {
  __shared__ _Float16 tile[64][68];
  int p  = blockIdx.y;
  int t0 = blockIdx.x * 64;
  int tid = threadIdx.x;
  int r = tid >> 3, c = (tid & 7) * 8;
#pragma unroll
  for (int it = 0; it < 2; ++it) {
    int rr = r + it * 32;
    *(ui4*)&tile[rr][c] = *(const ui4*)&Vd[((size_t)p * T_SEQ + t0 + rr) * HDIM + c];
  }
  __syncthreads();
#pragma unroll
  for (int it = 0; it < 2; ++it) {
    int d = r + it * 32;
    half8 o;
#pragma unroll
    for (int j = 0; j < 8; ++j) o[j] = tile[c + j][d];
    *(half8*)&Vt[((size_t)p * HDIM + d) * T_SEQ + t0 + c] = o;
  }
}

// ---------------- 128x128 MFMA GEMM: A staged in LDS, B-frags streamed from L2 ----
// MODE 0: epilogue -> Q(B,H,T,64)*(0.125*log2e), K(B,H,T,64), V(B,H,T,64)
// MODE 1: epilogue -> fp32 out + bias
template <int MODE>
__global__ __launch_bounds__(256) void gemm_kernel(
    const _Float16* __restrict__ A, const _Float16* __restrict__ Bfrag,
    const float* __restrict__ bias, int M, int N, int K,
    float* __restrict__ outF,
    _Float16* __restrict__ Qd, _Float16* __restrict__ Kd, _Float16* __restrict__ Vd) {
  __shared__ _Float16 As[128 * 32];   // 8 KB: A only
  int tid = threadIdx.x;
  int wave = tid >> 6, lane = tid & 63;
  int l15 = lane & 15, quad = lane >> 4;
  int wm = (wave & 1) * 64, wn = (wave >> 1) * 64;
  int m0 = blockIdx.x * 128, n0 = blockIdx.y * 128;   // x = M-dim: residents share B
  v4f zero = {0.f, 0.f, 0.f, 0.f};
  v4f acc[4][4];
#pragma unroll
  for (int i = 0; i < 4; ++i)
#pragma unroll
    for (int j = 0; j < 4; ++j) acc[i][j] = zero;

  int ar0 = tid >> 2;          // per-block row 0..63 (chunk 1: +64)
  int akc = (tid & 3) * 8;
  const _Float16* Ap = A + (size_t)(m0 + ar0) * K + akc;
  _Float16* AsW = As + wave * 512;            // lane L lands at +L*16B
  const int ktiles = K >> 5;
  const _Float16* Bp = Bfrag + (size_t)((n0 + wn) >> 4) * ktiles * 512 + lane * 8;

  for (int kt = 0; kt < ktiles; ++kt) {
    half8 bf[4];
#pragma unroll
    for (int ni = 0; ni < 4; ++ni)
      bf[ni] = *(const half8*)(Bp + ((size_t)ni * ktiles + kt) * 512);
    __syncthreads();
    load_lds16(Ap + kt * 32,                  AsW);
    load_lds16(Ap + kt * 32 + (size_t)64 * K, AsW + 2048);
    __syncthreads();
    half8 af[4];
#pragma unroll
    for (int i = 0; i < 4; ++i)
      af[i] = *(const half8*)&As[(wm + i * 16 + l15) * 32 + quad * 8];
#pragma unroll
    for (int mi = 0; mi < 4; ++mi)
#pragma unroll
      for (int ni = 0; ni < 4; ++ni)
        acc[mi][ni] = __builtin_amdgcn_mfma_f32_16x16x32_f16(af[mi], bf[ni], acc[mi][ni], 0, 0, 0);
  }
  // epilogue: C layout row=quad*4+r, col=l15
  float bv[4];
#pragma unroll
  for (int ni = 0; ni < 4; ++ni) bv[ni] = bias[n0 + wn + ni * 16 + l15];
#pragma unroll
  for (int mi = 0; mi < 4; ++mi) {
#pragma unroll
    for (int ni = 0; ni < 4; ++ni) {
      int n = n0 + wn + ni * 16 + l15;
#pragma unroll
      for (int r = 0; r < 4; ++r) {
        int m = m0 + wm + mi * 16 + quad * 4 + r;
        float v = acc[mi][ni][r] + bv[ni];
        if (MODE == 1) {
          outF[(size_t)m * N + n] = v;
        } else {
          int b = m >> 10, t = m & 1023;
          int h = (n >> 6) & 15, d = n & 63;
          size_t idx = ((size_t)(b * NHEAD + h) * T_SEQ + t) * HDIM + d;
          // 0.125 * log2(e): softmax runs in exp2 domain
          if (n < 1024)        Qd[idx] = (_Float16)(v * 0.18033688f);
          else if (n < 2048)   Kd[idx] = (_Float16)v;
          else                 Vd[idx] = (_Float16)v;
        }
      }
    }
  }
}

// ------- flash attention, S^T formulation: 64 q-rows/block (4 waves), 64-key tiles ------
// S^T = K Q^T  (A=K, B=Q): lane owns ONE q-row (col=l15), 16 keys in regs ->
// softmax reductions are in-lane + 2 cross-quad shuffles. O^T = V^T P^T.
__global__ __launch_bounds__(256) void attn_kernel(const _Float16* __restrict__ Qg,
                                                   const _Float16* __restrict__ Kk,
                                                   const _Float16* __restrict__ Vt,
                                                   const int* __restrict__ x_lens,
                                                   _Float16* __restrict__ att) {
  __shared__ _Float16 Ks[2][64 * 32];   // [d-half][key*32 + chunk]
  __shared__ _Float16 Vs[2][64 * 32];   // [key-half][d*32 + chunk]
  __shared__ _Float16 Pb[4][16 * 72];   // per-wave roundtrip: [q_local][key or d]
  int blk = blockIdx.x;
  int qt = blk >> 7;          // high bits -> per-CU qt mix for balance
  int bh = blk & 127;
  int h  = bh & 15;
  int b  = bh >> 4;
  int t0 = qt * 64;
  int len = x_lens[b];
  int tid = threadIdx.x;
  int wave = tid >> 6, lane = tid & 63;
  int l15 = lane & 15, quad = lane >> 4;
  size_t plane = (size_t)(b * NHEAD + h) * (T_SEQ * HDIM);
  int qrow = t0 + wave * 16;
  int qabs = qrow + l15;
  const _Float16* Qp = Qg + plane + (size_t)qabs * HDIM + quad * 8;
  half8 qf0 = *(const half8*)Qp;          // B-frag: Q[q=l15][d=quad*8+j]
  half8 qf1 = *(const half8*)(Qp + 32);
  v4f zero = {0.f, 0.f, 0.f, 0.f};
  float m_i = -1e30f, l_i = 0.f;          // per-lane: one q-row
  v4f Ov[4];                              // O^T C-layout: row d=16nt+quad*4+r, col q=l15
#pragma unroll
  for (int nt = 0; nt < 4; ++nt) Ov[nt] = zero;

  int jmaxb = min(t0 + 63, len - 1);
  int ntile = (jmaxb >> 6) + 1;
  int wjmax = min(qrow + 15, len - 1);

  // staging: 16 units of 1KB; wave w handles units w*4..w*4+3
  const _Float16* src[4];
  _Float16* dst[4];
  int strd[4];
#pragma unroll
  for (int i = 0; i < 4; ++i) {
    int u = wave * 4 + i;
    int q = u & 3, hf = (u >> 2) & 1;
    if (u < 8) {   // K: row q*16+(lane>>2), d = hf*32+(lane&3)*8
      src[i] = Kk + plane + (size_t)(q * 16 + (lane >> 2)) * HDIM + hf * 32 + (lane & 3) * 8;
      dst[i] = &Ks[hf][0] + q * 512;
      strd[i] = 64 * HDIM;
    } else {       // V^T: d-row q*16+(lane>>2), key = hf*32+(lane&3)*8
      src[i] = Vt + plane + (size_t)(q * 16 + (lane >> 2)) * T_SEQ + hf * 32 + (lane & 3) * 8;
      dst[i] = &Vs[hf][0] + q * 512;
      strd[i] = 64;
    }
  }

  for (int jt = 0; jt < ntile; ++jt) {
    int j0 = jt * 64;
    __syncthreads();
#pragma unroll
    for (int i = 0; i < 4; ++i) {
      load_lds16(src[i], dst[i]);
      src[i] += strd[i];
    }
    __syncthreads();
    if (j0 <= wjmax) {
      // S^T tiles: s[nt][r] = S[q=l15][key = j0 + nt*16 + quad*4 + r]
      v4f s[4];
#pragma unroll
      for (int nt = 0; nt < 4; ++nt) {
        s[nt] = zero;
        half8 k0 = *(const half8*)&Ks[0][(nt * 16 + l15) * 32 + quad * 8];
        half8 k1 = *(const half8*)&Ks[1][(nt * 16 + l15) * 32 + quad * 8];
        s[nt] = __builtin_amdgcn_mfma_f32_16x16x32_f16(k0, qf0, s[nt], 0, 0, 0);
        s[nt] = __builtin_amdgcn_mfma_f32_16x16x32_f16(k1, qf1, s[nt], 0, 0, 0);
      }
      float mnew = m_i;
      bool full = (j0 + 63 <= qrow) && (j0 + 63 < len);   // wave-uniform fast path
      if (full) {
#pragma unroll
        for (int nt = 0; nt < 4; ++nt)
#pragma unroll
          for (int r = 0; r < 4; ++r)
            mnew = fmaxf(mnew, s[nt][r]);
      } else {
#pragma unroll
        for (int nt = 0; nt < 4; ++nt) {
#pragma unroll
          for (int r = 0; r < 4; ++r) {
            int key = j0 + nt * 16 + quad * 4 + r;
            float v = (key <= qabs && key < len) ? s[nt][r] : -1e30f;
            s[nt][r] = v;
            mnew = fmaxf(mnew, v);
          }
        }
      }
      // cross-quad butterfly (lanes with same l15 share the q-row)
      mnew = fmaxf(mnew, __shfl_xor(mnew, 16));
      mnew = fmaxf(mnew, __shfl_xor(mnew, 32));
      float alpha = exp2f(m_i - mnew);
      m_i = mnew;
      float rsum = 0.f;
#pragma unroll
      for (int nt = 0; nt < 4; ++nt)
#pragma unroll
        for (int r = 0; r < 4; ++r) {
          float p = exp2f(s[nt][r] - mnew);
          s[nt][r] = p;
          rsum += p;
        }
      rsum += __shfl_xor(rsum, 16);
      rsum += __shfl_xor(rsum, 32);
      l_i = l_i * alpha + rsum;
#pragma unroll
      for (int nt = 0; nt < 4; ++nt)
#pragma unroll
        for (int r = 0; r < 4; ++r) Ov[nt][r] *= alpha;
      // P^T (C-layout) -> Pb[q][key] -> B-frag reads (wave-local)
#pragma unroll
      for (int nt = 0; nt < 4; ++nt) {
        half4h pk;
#pragma unroll
        for (int r = 0; r < 4; ++r) pk[r] = (_Float16)s[nt][r];
        *(half4h*)&Pb[wave][l15 * 72 + nt * 16 + quad * 4] = pk;
      }
      asm volatile("s_waitcnt lgkmcnt(0)" ::: "memory");
      half8 pf0 = *(const half8*)&Pb[wave][l15 * 72 + quad * 8];        // keys 0..31
      half8 pf1 = *(const half8*)&Pb[wave][l15 * 72 + 32 + quad * 8];   // keys 32..63
#pragma unroll
      for (int nt = 0; nt < 4; ++nt) {
        half8 v0 = *(const half8*)&Vs[0][(nt * 16 + l15) * 32 + quad * 8];
        half8 v1 = *(const half8*)&Vs[1][(nt * 16 + l15) * 32 + quad * 8];
        Ov[nt] = __builtin_amdgcn_mfma_f32_16x16x32_f16(v0, pf0, Ov[nt], 0, 0, 0);
        Ov[nt] = __builtin_amdgcn_mfma_f32_16x16x32_f16(v1, pf1, Ov[nt], 0, 0, 0);
      }
    }
  }
  // epilogue: O^T regs -> Pb[q_local][d] -> coalesced global stores
  float inv = 1.0f / l_i;
#pragma unroll
  for (int nt = 0; nt < 4; ++nt) {
    half4h ok;
#pragma unroll
    for (int r = 0; r < 4; ++r) ok[r] = (_Float16)(Ov[nt][r] * inv);
    *(half4h*)&Pb[wave][l15 * 72 + nt * 16 + quad * 4] = ok;
  }
  asm volatile("s_waitcnt lgkmcnt(0)" ::: "memory");
  int r0 = lane >> 3, c0 = (lane & 7) * 8;
  half8 o0 = *(const half8*)&Pb[wave][r0 * 72 + c0];
  half8 o1 = *(const half8*)&Pb[wave][(r0 + 8) * 72 + c0];
  *(half8*)&att[((size_t)(b * T_SEQ) + qrow + r0) * D_MODEL + h * HDIM + c0] = o0;
  *(half8*)&att[((size_t)(b * T_SEQ) + qrow + r0 + 8) * D_MODEL + h * HDIM + c0] = o1;
}

extern "C" void kernel_launch(void* const* d_in, const int* in_sizes, int n_in,
                              void* d_out, int out_size, void* d_ws, size_t ws_size,
                              hipStream_t stream) {
  const float* x        = (const float*)d_in[0];
  const int*   x_lens   = (const int*)d_in[1];
  const float* ln_gamma = (const float*)d_in[2];
  const float* ln_beta  = (const float*)d_in[3];
  const float* w_qkv    = (const float*)d_in[4];
  const float* b_qkv    = (const float*)d_in[5];
  const float* w_out    = (const float*)d_in[6];
  const float* b_out    = (const float*)d_in[7];
  float* out = (float*)d_out;

  char* w = (char*)d_ws;
  _Float16* xn    = (_Float16*)w; w += (size_t)8192 * 1024 * 2;   // 16MB (aliased by Vt later)
  _Float16* BfQKV = (_Float16*)w; w += (size_t)3072 * 1024 * 2;   // 6MB
  _Float16* BfOut = (_Float16*)w; w += (size_t)1024 * 1024 * 2;   // 2MB
  _Float16* Qd    = (_Float16*)w; w += (size_t)8192 * 1024 * 2;
  _Float16* Kd    = (_Float16*)w; w += (size_t)8192 * 1024 * 2;
  _Float16* Vd    = (_Float16*)w; w += (size_t)8192 * 1024 * 2;
  _Float16* att   = (_Float16*)w; w += (size_t)8192 * 1024 * 2;
  _Float16* Vt    = xn;   // xn dead after gemm<0>; reuse for V^T

  fragize_kernel<<<(3072 * 1024 / 8) / 256, 256, 0, stream>>>(w_qkv, BfQKV, 3072, 1024);
  fragize_kernel<<<(1024 * 1024 / 8) / 256, 256, 0, stream>>>(w_out, BfOut, 1024, 1024);
  ln_kernel<<<8192, 256, 0, stream>>>(x, ln_gamma, ln_beta, xn);
  gemm_kernel<0><<<dim3(8192 / 128, 3072 / 128), 256, 0, stream>>>(
      xn, BfQKV, b_qkv, 8192, 3072, 1024, nullptr, Qd, Kd, Vd);
  vtrans_kernel<<<dim3(16, 128), 256, 0, stream>>>(Vd, Vt);
  attn_kernel<<<2048, 256, 0, stream>>>(Qd, Kd, Vt, x_lens, att);
  gemm_kernel<1><<<dim3(8192 / 128, 1024 / 128), 256, 0, stream>>>(
      att, BfOut, b_out, 8192, 1024, 1024, out, nullptr, nullptr, nullptr);
}